// Round 4
// baseline (220.169 us; speedup 1.0000x reference)
//
#include <hip/hip_runtime.h>
#include <hip/hip_bf16.h>
#include <stdint.h>

typedef unsigned short u16;
typedef __attribute__((ext_vector_type(8))) short short8;   // 8 bf16 (4 VGPRs)
typedef __attribute__((ext_vector_type(4))) short short4v;  // 4 bf16 (2 VGPRs)
typedef __attribute__((ext_vector_type(4))) float f32x4;    // MFMA C/D

#define NB 2
#define NC 128
#define NHD 4      // heads
#define HD 32      // head dim
#define NN 3136    // H*W
#define NA 49      // agent tokens
#define NSPLIT 4   // flash K-split
#define SCALE 0.17677669529663687f  // 1/sqrt(32)
#define LOG2E 1.4426950408889634f
#define QSC (SCALE * LOG2E)

__device__ inline u16 bfb(float f) {
    __hip_bfloat16 h = __float2bfloat16(f);
    return *(u16*)&h;
}
__device__ inline float b2f(u16 w) {
    return __uint_as_float(((uint32_t)w) << 16);
}
// pack 4 floats -> 4 bf16 (j-order: [0]=low of dword0)
__device__ inline short4v pack4(float a, float b, float c, float d) {
    union { short4v s; __hip_bfloat162 h[2]; } u;
    u.h[0] = __float22bfloat162_rn(make_float2(a, b));
    u.h[1] = __float22bfloat162_rn(make_float2(c, d));
    return u.s;
}
__device__ inline float ldf(const void* p, size_t i, int f) {
    return f ? b2f(((const u16*)p)[i]) : ((const float*)p)[i];
}

// ---------------------------------------------------------------------------
// dtype detection (bf16 vs fp32 inputs)
__global__ void k_detect(const u16* __restrict__ raw, int* __restrict__ flag) {
    __shared__ int cnt;
    if (threadIdx.x == 0) cnt = 0;
    __syncthreads();
    u16 w = raw[threadIdx.x * 97];
    float f = b2f(w);
    float a = fabsf(f);
    if (a >= 1e-4f && a <= 100.0f) atomicAdd(&cnt, 1);
    __syncthreads();
    if (threadIdx.x == 0) *flag = (cnt >= 230) ? 1 : 0;
}

// ---------------------------------------------------------------------------
// x convert: xf fp32 [b][c][n] (for agent pool) + xT bf16 [b][n][c] (for QKV
// MFMA B-frags). Tile transpose through LDS. grid (196, NB), block 256.
__global__ __launch_bounds__(256) void k_conv_x(const void* __restrict__ xr,
                                                float* __restrict__ xf,
                                                u16* __restrict__ xT,
                                                const int* __restrict__ flag) {
    __shared__ u16 tile[128][18];
    int b = blockIdx.y;
    int n0 = blockIdx.x * 16;
    int t = threadIdx.x;
    int f = *flag;
    int c = t >> 1, nh = (t & 1) * 8;
    size_t src = ((size_t)(b * 128 + c)) * NN + n0 + nh;
    float a[8];
#pragma unroll
    for (int i = 0; i < 8; ++i) a[i] = ldf(xr, src + i, f);
#pragma unroll
    for (int i = 0; i < 8; ++i) xf[src + i] = a[i];
#pragma unroll
    for (int i = 0; i < 8; ++i) tile[c][nh + i] = bfb(a[i]);
    __syncthreads();
    int n = t >> 4, c0 = (t & 15) * 8;
    short8 o;
#pragma unroll
    for (int i = 0; i < 8; ++i) o[i] = (short)tile[c0 + i][n];
    *(short8*)&xT[((size_t)b * NN + n0 + n) * 128 + c0] = o;
}

// ---------------------------------------------------------------------------
// weight convert: wbf bf16 (384x128), wpt fp32 transposed [c][o], biases.
// grid 258 blocks x 256.
__global__ void k_conv_w(const void* __restrict__ wq, const void* __restrict__ wp,
                         const void* __restrict__ bp, const void* __restrict__ g,
                         const void* __restrict__ bb,
                         u16* __restrict__ wbf, float* __restrict__ wpt,
                         float* __restrict__ bgb, const int* __restrict__ flag) {
    int bx = blockIdx.x, t = threadIdx.x;
    int f = *flag;
    if (bx < 192) {
        int i = bx * 256 + t;
        wbf[i] = bfb(ldf(wq, i, f));
    } else if (bx < 256) {
        int i = (bx - 192) * 256 + t;
        wpt[(i & 127) * 128 + (i >> 7)] = ldf(wp, i, f);
    } else {
        int i = (bx - 256) * 256 + t;
        if (i < 128)      bgb[i] = ldf(bp, i, f);
        else if (i < 256) bgb[i] = ldf(g, i - 128, f);
        else if (i < 384) bgb[i] = ldf(bb, i - 256, f);
    }
}

// ---------------------------------------------------------------------------
// QKV via bf16 MFMA: [384x128] @ [128xN]. Each wave: 16 o x 64 n, K=128 in
// 4 frags. Prefetched B-frags + sched fence so loads stay lifted.
// q bf16 [b,h,n,d] PRESCALED by SCALE*LOG2E; k bf16 [b,h,n,d];
// v bf16 TRANSPOSED [b,h,d,n]. grid (49, 6, NB) x 256.
__global__ __launch_bounds__(256, 4) void k_qkv2(const u16* __restrict__ xT,
                                                 const u16* __restrict__ wbf,
                                                 u16* __restrict__ qb,
                                                 u16* __restrict__ kbf,
                                                 u16* __restrict__ vtb) {
    int b = blockIdx.z;
    int n0 = blockIdx.x * 64;
    int w = threadIdx.x >> 6, lane = threadIdx.x & 63;
    int c = lane & 15, u = lane >> 4;
    int o0 = blockIdx.y * 64 + w * 16;
    const f32x4 z = {0.f, 0.f, 0.f, 0.f};
    short8 af0 = *(const short8*)&wbf[(o0 + c) * 128 +  0 + u * 8];
    short8 af1 = *(const short8*)&wbf[(o0 + c) * 128 + 32 + u * 8];
    short8 af2 = *(const short8*)&wbf[(o0 + c) * 128 + 64 + u * 8];
    short8 af3 = *(const short8*)&wbf[(o0 + c) * 128 + 96 + u * 8];
    int tq = o0 >> 7, h = (o0 >> 5) & 3, d0 = (o0 & 31) + u * 4;
    size_t bh = (size_t)b * NHD + h;
    const u16* xb = &xT[(size_t)b * NN * 128];
    // prefetch nt=0
    int n = n0 + c;
    short8 bf0 = *(const short8*)&xb[(size_t)n * 128 +  0 + u * 8];
    short8 bf1 = *(const short8*)&xb[(size_t)n * 128 + 32 + u * 8];
    short8 bf2 = *(const short8*)&xb[(size_t)n * 128 + 64 + u * 8];
    short8 bf3 = *(const short8*)&xb[(size_t)n * 128 + 96 + u * 8];
#pragma unroll 1
    for (int nt = 0; nt < 4; ++nt) {
        int ntn = (nt + 1 < 4) ? nt + 1 : 0;
        int n2 = n0 + ntn * 16 + c;
        short8 nb0 = *(const short8*)&xb[(size_t)n2 * 128 +  0 + u * 8];
        short8 nb1 = *(const short8*)&xb[(size_t)n2 * 128 + 32 + u * 8];
        short8 nb2 = *(const short8*)&xb[(size_t)n2 * 128 + 64 + u * 8];
        short8 nb3 = *(const short8*)&xb[(size_t)n2 * 128 + 96 + u * 8];
        asm volatile("" ::: "memory");
        int nc_ = n0 + nt * 16 + c;
        f32x4 acc = z;
        acc = __builtin_amdgcn_mfma_f32_16x16x32_bf16(af0, bf0, acc, 0, 0, 0);
        acc = __builtin_amdgcn_mfma_f32_16x16x32_bf16(af1, bf1, acc, 0, 0, 0);
        acc = __builtin_amdgcn_mfma_f32_16x16x32_bf16(af2, bf2, acc, 0, 0, 0);
        acc = __builtin_amdgcn_mfma_f32_16x16x32_bf16(af3, bf3, acc, 0, 0, 0);
        if (tq == 0) {
            *(short4v*)&qb[(bh * NN + nc_) * HD + d0] =
                pack4(acc[0] * QSC, acc[1] * QSC, acc[2] * QSC, acc[3] * QSC);
        } else if (tq == 1) {
            *(short4v*)&kbf[(bh * NN + nc_) * HD + d0] =
                pack4(acc[0], acc[1], acc[2], acc[3]);
        } else {
#pragma unroll
            for (int r = 0; r < 4; ++r)
                vtb[(bh * HD + d0 + r) * NN + nc_] = bfb(acc[r]);
        }
        bf0 = nb0; bf1 = nb1; bf2 = nb2; bf3 = nb3;
    }
}

// ---------------------------------------------------------------------------
// agent tokens: 8x8 block mean -> agb bf16 [b,h][64(pad)][32] and
// agTb bf16 [b,h][32][64(pad)], pads zeroed. grid 79 x 256.
__global__ void k_agent(const float* __restrict__ xf, u16* __restrict__ agb,
                        u16* __restrict__ agT) {
    int idx = blockIdx.x * 256 + threadIdx.x;
    const int NPOOL = NB * NC * NA;   // 12544
    if (idx < NPOOL) {
        int b = idx / (NC * NA);
        int r = idx % (NC * NA);
        int c = r / NA;
        int a = r % NA;
        int ai = a / 7, aj = a % 7;
        const float* base = xf + (b * NC + c) * NN + ai * 8 * 56 + aj * 8;
        float s = 0.f;
#pragma unroll
        for (int uu = 0; uu < 8; ++uu) {
            float4 v0 = *(const float4*)&base[uu * 56];
            float4 v1 = *(const float4*)&base[uu * 56 + 4];
            s += v0.x + v0.y + v0.z + v0.w + v1.x + v1.y + v1.z + v1.w;
        }
        int h = c >> 5, d = c & 31;
        int bh = b * NHD + h;
        u16 val = bfb(s * (1.f / 64.f));
        agb[bh * 2048 + a * 32 + d] = val;
        agT[bh * 2048 + d * 64 + a] = val;
    } else {
        int j = idx - NPOOL;
        if (j < 3840) {            // agb pad rows 49..63
            int bh = j / 480, rem = j % 480;
            int a = 49 + rem / 32, d = rem % 32;
            agb[bh * 2048 + a * 32 + d] = 0;
        } else if (j < 7680) {     // agT pad cols 49..63
            j -= 3840;
            int bh = j / 480, rem = j % 480;
            int a = 49 + rem / 32, d = rem % 32;
            agT[bh * 2048 + d * 64 + a] = 0;
        }
    }
}

// ---------------------------------------------------------------------------
// stage 1 via MFMA. S^T = Ag·Q^T (4 m-tiles, agents padded to 64); C-frag of
// S^T == B-operand layout of 16x16x16 MFMA, so normalized P feeds qc^T =
// Ag^T·P^T directly. qcb bf16 prescaled by SCALE*LOG2E. grid (49,4,NB) x 256.
__global__ __launch_bounds__(256, 4) void k_stage1_2(const u16* __restrict__ qb,
                                                     const u16* __restrict__ agb,
                                                     const u16* __restrict__ agT,
                                                     u16* __restrict__ qcb) {
    int b = blockIdx.z, h = blockIdx.y;
    int w = threadIdx.x >> 6, lane = threadIdx.x & 63;
    int c = lane & 15, u = lane >> 4;
    int q0 = blockIdx.x * 64 + w * 16;
    size_t bh = (size_t)b * NHD + h;
    const u16* aB = agb + bh * 2048;
    const u16* aT = agT + bh * 2048;
    const f32x4 z = {0.f, 0.f, 0.f, 0.f};
    short8 qf = *(const short8*)&qb[(bh * NN + q0 + c) * HD + u * 8];
    f32x4 st[4];
#pragma unroll
    for (int t = 0; t < 4; ++t) {
        short8 afr = *(const short8*)&aB[(t * 16 + c) * 32 + u * 8];
        st[t] = __builtin_amdgcn_mfma_f32_16x16x32_bf16(afr, qf, z, 0, 0, 0);
    }
    float e[4][4];
    float lsum = 0.f;
#pragma unroll
    for (int t = 0; t < 4; ++t)
#pragma unroll
        for (int r = 0; r < 4; ++r) {
            float v = __builtin_amdgcn_exp2f(st[t][r]);
            if (t == 3 && !(u == 0 && r == 0)) v = 0.f;   // agents >= 49
            e[t][r] = v;
            lsum += v;
        }
    lsum += __shfl_xor(lsum, 16);
    lsum += __shfl_xor(lsum, 32);
    float linv = 1.f / lsum;
    f32x4 qlo = z, qhi = z;
#pragma unroll
    for (int t = 0; t < 4; ++t) {
        short4v pf = pack4(e[t][0] * linv, e[t][1] * linv, e[t][2] * linv, e[t][3] * linv);
        short4v alo = *(const short4v*)&aT[c * 64 + t * 16 + u * 4];
        short4v ahi = *(const short4v*)&aT[(c + 16) * 64 + t * 16 + u * 4];
        qlo = __builtin_amdgcn_mfma_f32_16x16x16bf16_1k(alo, pf, qlo, 0, 0, 0);
        qhi = __builtin_amdgcn_mfma_f32_16x16x16bf16_1k(ahi, pf, qhi, 0, 0, 0);
    }
    u16* dst = &qcb[(bh * NN + q0 + c) * HD];
    *(short4v*)&dst[u * 4]      = pack4(qlo[0] * QSC, qlo[1] * QSC, qlo[2] * QSC, qlo[3] * QSC);
    *(short4v*)&dst[16 + u * 4] = pack4(qhi[0] * QSC, qhi[1] * QSC, qhi[2] * QSC, qhi[3] * QSC);
}

// ---------------------------------------------------------------------------
// stage 2 flash, zero-LDS, 64 keys/iter (4 independent S-chains). 1-deep
// register prefetch (12 loads in flight) + sched fence; launch_bounds(256,4)
// gives the allocator a 128-VGPR budget so the pipeline isn't serialized.
// K-split NSPLIT at 64-key granularity. grid (49, NHD*NSPLIT, NB) x 256.
__global__ __launch_bounds__(256, 4) void k_flash3(const u16* __restrict__ qc,
                                                   const u16* __restrict__ kb,
                                                   const u16* __restrict__ vt,
                                                   float* __restrict__ op,
                                                   float* __restrict__ lp) {
    int b = blockIdx.z;
    int h = blockIdx.y & 3;
    int s = blockIdx.y >> 2;
    int wave = threadIdx.x >> 6, lane = threadIdx.x & 63;
    int c = lane & 15, u = lane >> 4;
    int q0 = blockIdx.x * 64 + wave * 16;
    size_t bh = (size_t)b * NHD + h;
    const u16* kbase = kb + bh * NN * HD;
    const u16* vb0p = vt + bh * (size_t)HD * NN + (size_t)c * NN;
    const u16* vb1p = vt + bh * (size_t)HD * NN + (size_t)(c + 16) * NN;
    short8 qfrag = *(const short8*)(qc + (bh * NN + q0 + c) * HD + u * 8);
    const f32x4 z = {0.f, 0.f, 0.f, 0.f};
    f32x4 o0 = z, o1 = z;
    float lpart = 0.f;
    int u0 = (s * 49) / NSPLIT, u1 = ((s + 1) * 49) / NSPLIT;   // 64-key units
    // prefetch unit u0
    int kk = u0 * 64;
    short8  kf0 = *(const short8*)(kbase + (size_t)(kk +      c) * HD + u * 8);
    short8  kf1 = *(const short8*)(kbase + (size_t)(kk + 16 + c) * HD + u * 8);
    short8  kf2 = *(const short8*)(kbase + (size_t)(kk + 32 + c) * HD + u * 8);
    short8  kf3 = *(const short8*)(kbase + (size_t)(kk + 48 + c) * HD + u * 8);
    short4v va0 = *(const short4v*)(vb0p + kk +      u * 4);
    short4v va1 = *(const short4v*)(vb0p + kk + 16 + u * 4);
    short4v va2 = *(const short4v*)(vb0p + kk + 32 + u * 4);
    short4v va3 = *(const short4v*)(vb0p + kk + 48 + u * 4);
    short4v vc0 = *(const short4v*)(vb1p + kk +      u * 4);
    short4v vc1 = *(const short4v*)(vb1p + kk + 16 + u * 4);
    short4v vc2 = *(const short4v*)(vb1p + kk + 32 + u * 4);
    short4v vc3 = *(const short4v*)(vb1p + kk + 48 + u * 4);
#pragma unroll 1
    for (int ku = u0; ku < u1; ++ku) {
        int kun = (ku + 1 < u1) ? ku + 1 : u0;   // clamped prefetch index
        int kn = kun * 64;
        short8  nk0 = *(const short8*)(kbase + (size_t)(kn +      c) * HD + u * 8);
        short8  nk1 = *(const short8*)(kbase + (size_t)(kn + 16 + c) * HD + u * 8);
        short8  nk2 = *(const short8*)(kbase + (size_t)(kn + 32 + c) * HD + u * 8);
        short8  nk3 = *(const short8*)(kbase + (size_t)(kn + 48 + c) * HD + u * 8);
        short4v na0 = *(const short4v*)(vb0p + kn +      u * 4);
        short4v na1 = *(const short4v*)(vb0p + kn + 16 + u * 4);
        short4v na2 = *(const short4v*)(vb0p + kn + 32 + u * 4);
        short4v na3 = *(const short4v*)(vb0p + kn + 48 + u * 4);
        short4v nc0 = *(const short4v*)(vb1p + kn +      u * 4);
        short4v nc1 = *(const short4v*)(vb1p + kn + 16 + u * 4);
        short4v nc2 = *(const short4v*)(vb1p + kn + 32 + u * 4);
        short4v nc3 = *(const short4v*)(vb1p + kn + 48 + u * 4);
        asm volatile("" ::: "memory");
        f32x4 st0 = __builtin_amdgcn_mfma_f32_16x16x32_bf16(kf0, qfrag, z, 0, 0, 0);
        f32x4 st1 = __builtin_amdgcn_mfma_f32_16x16x32_bf16(kf1, qfrag, z, 0, 0, 0);
        f32x4 st2 = __builtin_amdgcn_mfma_f32_16x16x32_bf16(kf2, qfrag, z, 0, 0, 0);
        f32x4 st3 = __builtin_amdgcn_mfma_f32_16x16x32_bf16(kf3, qfrag, z, 0, 0, 0);
        float e00 = __builtin_amdgcn_exp2f(st0[0]);
        float e01 = __builtin_amdgcn_exp2f(st0[1]);
        float e02 = __builtin_amdgcn_exp2f(st0[2]);
        float e03 = __builtin_amdgcn_exp2f(st0[3]);
        float e10 = __builtin_amdgcn_exp2f(st1[0]);
        float e11 = __builtin_amdgcn_exp2f(st1[1]);
        float e12 = __builtin_amdgcn_exp2f(st1[2]);
        float e13 = __builtin_amdgcn_exp2f(st1[3]);
        float e20 = __builtin_amdgcn_exp2f(st2[0]);
        float e21 = __builtin_amdgcn_exp2f(st2[1]);
        float e22 = __builtin_amdgcn_exp2f(st2[2]);
        float e23 = __builtin_amdgcn_exp2f(st2[3]);
        float e30 = __builtin_amdgcn_exp2f(st3[0]);
        float e31 = __builtin_amdgcn_exp2f(st3[1]);
        float e32 = __builtin_amdgcn_exp2f(st3[2]);
        float e33 = __builtin_amdgcn_exp2f(st3[3]);
        lpart += ((e00 + e01) + (e02 + e03)) + ((e10 + e11) + (e12 + e13))
               + ((e20 + e21) + (e22 + e23)) + ((e30 + e31) + (e32 + e33));
        short4v p0 = pack4(e00, e01, e02, e03);
        short4v p1 = pack4(e10, e11, e12, e13);
        short4v p2 = pack4(e20, e21, e22, e23);
        short4v p3 = pack4(e30, e31, e32, e33);
        o0 = __builtin_amdgcn_mfma_f32_16x16x16bf16_1k(va0, p0, o0, 0, 0, 0);
        o0 = __builtin_amdgcn_mfma_f32_16x16x16bf16_1k(va1, p1, o0, 0, 0, 0);
        o0 = __builtin_amdgcn_mfma_f32_16x16x16bf16_1k(va2, p2, o0, 0, 0, 0);
        o0 = __builtin_amdgcn_mfma_f32_16x16x16bf16_1k(va3, p3, o0, 0, 0, 0);
        o1 = __builtin_amdgcn_mfma_f32_16x16x16bf16_1k(vc0, p0, o1, 0, 0, 0);
        o1 = __builtin_amdgcn_mfma_f32_16x16x16bf16_1k(vc1, p1, o1, 0, 0, 0);
        o1 = __builtin_amdgcn_mfma_f32_16x16x16bf16_1k(vc2, p2, o1, 0, 0, 0);
        o1 = __builtin_amdgcn_mfma_f32_16x16x16bf16_1k(vc3, p3, o1, 0, 0, 0);
        kf0 = nk0; kf1 = nk1; kf2 = nk2; kf3 = nk3;
        va0 = na0; va1 = na1; va2 = na2; va3 = na3;
        vc0 = nc0; vc1 = nc1; vc2 = nc2; vc3 = nc3;
    }
    lpart += __shfl_xor(lpart, 16);
    lpart += __shfl_xor(lpart, 32);
    // O^T frags: lane holds O[q=c][d=u*4+r] (o0: d 0..15, o1: d 16..31)
    float* obase = op + (((size_t)(s * NB + b)) * NN + q0 + c) * NC + h * HD;
    *(f32x4*)&obase[u * 4]      = o0;
    *(f32x4*)&obase[16 + u * 4] = o1;
    if (u == 0)
        lp[(((size_t)(s * NB + b)) * NHD + h) * NN + q0 + c] = lpart;
}

// ---------------------------------------------------------------------------
// combine NSPLIT partials + normalize + proj (fp32) + LayerNorm + NCHW store.
__global__ __launch_bounds__(128) void k_proj_ln(const float* __restrict__ op,
                                                 const float* __restrict__ lp,
                                                 const float* __restrict__ wpt,
                                                 const float* __restrict__ bgb,
                                                 void* __restrict__ out,
                                                 const int* __restrict__ flag) {
    __shared__ float row[NC];
    __shared__ float red[4];
    int bn = blockIdx.x;
    int b = bn / NN, n = bn % NN;
    int o = threadIdx.x;
    int h = o >> 5;
    float lsum = 0.f, oval = 0.f;
#pragma unroll
    for (int s = 0; s < NSPLIT; ++s) {
        lsum += lp[(((size_t)(s * NB + b)) * NHD + h) * NN + n];
        oval += op[(((size_t)(s * NB + b)) * NN + n) * NC + o];
    }
    row[o] = oval / lsum;
    __syncthreads();
    float acc = bgb[o];
#pragma unroll 8
    for (int c = 0; c < NC; ++c) acc += row[c] * wpt[c * NC + o];
    float s1 = acc, s2 = acc * acc;
#pragma unroll
    for (int off = 32; off; off >>= 1) {
        s1 += __shfl_xor(s1, off);
        s2 += __shfl_xor(s2, off);
    }
    if ((o & 63) == 0) { red[(o >> 6) * 2] = s1; red[(o >> 6) * 2 + 1] = s2; }
    __syncthreads();
    float mu  = (red[0] + red[2]) * (1.f / NC);
    float ex2 = (red[1] + red[3]) * (1.f / NC);
    float rstd = rsqrtf(ex2 - mu * mu + 1e-5f);
    float val = (acc - mu) * rstd * bgb[128 + o] + bgb[256 + o];
    size_t oidx = ((size_t)(b * NC + o)) * NN + n;
    if (*flag) ((__hip_bfloat16*)out)[oidx] = __float2bfloat16(val);
    else       ((float*)out)[oidx] = val;
}

// ---------------------------------------------------------------------------
extern "C" void kernel_launch(void* const* d_in, const int* in_sizes, int n_in,
                              void* d_out, int out_size, void* d_ws, size_t ws_size,
                              hipStream_t stream) {
    const void* x_raw  = d_in[0];
    const void* wq_raw = d_in[1];
    const void* wp_raw = d_in[2];
    const void* bp_raw = d_in[3];
    const void* lg_raw = d_in[4];
    const void* lb_raw = d_in[5];

    float* ws   = (float*)d_ws;
    int*   flag = (int*)d_ws;
    float* xf   = ws + 16;                         // 802816 f
    float* wpt  = xf + NB * NC * NN;               // 16384 f
    float* bgb  = wpt + NC * NC;                   // 512 f
    float* op   = bgb + 512;                       // NSPLIT*NB*NN*NC f
    float* lp   = op + (size_t)NSPLIT * NB * NN * NC;  // NSPLIT*NB*NHD*NN f
    u16*   xT   = (u16*)(lp + (size_t)NSPLIT * NB * NHD * NN);
    u16*   wbf  = xT + (size_t)NB * NN * NC;       // 49152 u16
    u16*   qb   = wbf + 3 * NC * NC;               // 802816 u16 each:
    u16*   kbf  = qb + (size_t)NB * NHD * NN * HD;
    u16*   vtb  = kbf + (size_t)NB * NHD * NN * HD;
    u16*   qcb  = vtb + (size_t)NB * NHD * NN * HD;
    u16*   agb  = qcb + (size_t)NB * NHD * NN * HD;  // 16384 u16
    u16*   agT  = agb + NB * NHD * 64 * 32;          // 16384 u16
    // total ~24.7 MB

    k_detect<<<1, 256, 0, stream>>>((const u16*)x_raw, flag);
    k_conv_x<<<dim3(NN / 16, NB), 256, 0, stream>>>(x_raw, xf, xT, flag);
    k_conv_w<<<258, 256, 0, stream>>>(wq_raw, wp_raw, bp_raw, lg_raw, lb_raw,
                                      wbf, wpt, bgb, flag);
    k_qkv2<<<dim3(NN / 64, 6, NB), 256, 0, stream>>>(xT, wbf, qb, kbf, vtb);
    k_agent<<<79, 256, 0, stream>>>(xf, agb, agT);
    k_stage1_2<<<dim3(NN / 64, NHD, NB), 256, 0, stream>>>(qb, agb, agT, qcb);
    k_flash3<<<dim3(NN / 64, NHD * NSPLIT, NB), 256, 0, stream>>>(qcb, kbf, vtb, op, lp);
    k_proj_ln<<<NB * NN, 128, 0, stream>>>(op, lp, wpt, bgb, d_out, flag);
}

// Round 5
// 141.286 us; speedup vs baseline: 1.5583x; 1.5583x over previous
//
#include <hip/hip_runtime.h>
#include <hip/hip_bf16.h>
#include <stdint.h>

typedef unsigned short u16;
typedef __attribute__((ext_vector_type(8))) short short8;   // 8 bf16 (4 VGPRs)
typedef __attribute__((ext_vector_type(4))) short short4v;  // 4 bf16 (2 VGPRs)
typedef __attribute__((ext_vector_type(4))) float f32x4;    // MFMA C/D

#define NB 2
#define NC 128
#define NHD 4      // heads
#define HD 32      // head dim
#define NN 3136    // H*W
#define NA 49      // agent tokens
#define NSPLIT 4   // flash K-split
#define NKP 3200   // padded key count (25 tiles of 128)
#define NTILE 25
#define SCALE 0.17677669529663687f  // 1/sqrt(32)
#define LOG2E 1.4426950408889634f
#define QSC (SCALE * LOG2E)

__device__ inline u16 bfb(float f) {
    __hip_bfloat16 h = __float2bfloat16(f);
    return *(u16*)&h;
}
__device__ inline float b2f(u16 w) {
    return __uint_as_float(((uint32_t)w) << 16);
}
__device__ inline short4v pack4(float a, float b, float c, float d) {
    union { short4v s; __hip_bfloat162 h[2]; } u;
    u.h[0] = __float22bfloat162_rn(make_float2(a, b));
    u.h[1] = __float22bfloat162_rn(make_float2(c, d));
    return u.s;
}
__device__ inline float ldf(const void* p, size_t i, int f) {
    return f ? b2f(((const u16*)p)[i]) : ((const float*)p)[i];
}
// async global->LDS, 16B per lane; lds dest = uniform base + lane*16
__device__ inline void gld16(const u16* g, u16* l) {
    __builtin_amdgcn_global_load_lds(
        (__attribute__((address_space(1))) void*)(g),
        (__attribute__((address_space(3))) void*)(l), 16, 0, 0);
}
// stage 8KB contiguous: 256 threads x 2 issues x 16B
__device__ inline void stage8k(const u16* g, u16* lds, int w, int lane) {
    gld16(g + (size_t)(w * 64 + lane) * 8,       lds + (size_t)w * 512);
    gld16(g + (size_t)(256 + w * 64 + lane) * 8, lds + 2048 + (size_t)w * 512);
}

// ---------------------------------------------------------------------------
__global__ void k_detect(const u16* __restrict__ raw, int* __restrict__ flag) {
    __shared__ int cnt;
    if (threadIdx.x == 0) cnt = 0;
    __syncthreads();
    u16 w = raw[threadIdx.x * 97];
    float f = b2f(w);
    float a = fabsf(f);
    if (a >= 1e-4f && a <= 100.0f) atomicAdd(&cnt, 1);
    __syncthreads();
    if (threadIdx.x == 0) *flag = (cnt >= 230) ? 1 : 0;
}

// ---------------------------------------------------------------------------
// x convert: xf fp32 [b][c][n] + xT bf16 [b][n][c]. grid (196, NB) x 256.
__global__ __launch_bounds__(256) void k_conv_x(const void* __restrict__ xr,
                                                float* __restrict__ xf,
                                                u16* __restrict__ xT,
                                                const int* __restrict__ flag) {
    __shared__ u16 tile[128][18];
    int b = blockIdx.y;
    int n0 = blockIdx.x * 16;
    int t = threadIdx.x;
    int f = *flag;
    int c = t >> 1, nh = (t & 1) * 8;
    size_t src = ((size_t)(b * 128 + c)) * NN + n0 + nh;
    float a[8];
#pragma unroll
    for (int i = 0; i < 8; ++i) a[i] = ldf(xr, src + i, f);
#pragma unroll
    for (int i = 0; i < 8; ++i) xf[src + i] = a[i];
#pragma unroll
    for (int i = 0; i < 8; ++i) tile[c][nh + i] = bfb(a[i]);
    __syncthreads();
    int n = t >> 4, c0 = (t & 15) * 8;
    short8 o;
#pragma unroll
    for (int i = 0; i < 8; ++i) o[i] = (short)tile[c0 + i][n];
    *(short8*)&xT[((size_t)b * NN + n0 + n) * 128 + c0] = o;
}

// ---------------------------------------------------------------------------
__global__ void k_conv_w(const void* __restrict__ wq, const void* __restrict__ wp,
                         const void* __restrict__ bp, const void* __restrict__ g,
                         const void* __restrict__ bb,
                         u16* __restrict__ wbf, float* __restrict__ wpt,
                         float* __restrict__ bgb, const int* __restrict__ flag) {
    int bx = blockIdx.x, t = threadIdx.x;
    int f = *flag;
    if (bx < 192) {
        int i = bx * 256 + t;
        wbf[i] = bfb(ldf(wq, i, f));
    } else if (bx < 256) {
        int i = (bx - 192) * 256 + t;
        wpt[(i & 127) * 128 + (i >> 7)] = ldf(wp, i, f);
    } else {
        int i = (bx - 256) * 256 + t;
        if (i < 128)      bgb[i] = ldf(bp, i, f);
        else if (i < 256) bgb[i] = ldf(g, i - 128, f);
        else if (i < 384) bgb[i] = ldf(bb, i - 256, f);
    }
}

// ---------------------------------------------------------------------------
// QKV via bf16 MFMA. Wave: 16 o x 32 n (2 n-tiles). grid (98, 6, NB) x 256.
// q bf16 [bh][n][d] prescaled QSC; k bf16 [bh][NKP(pad)][d];
// v bf16 pre-fragmented [bh][tile][sub][kquad][d][4].
__global__ __launch_bounds__(256, 4) void k_qkv2(const u16* __restrict__ xT,
                                                 const u16* __restrict__ wbf,
                                                 u16* __restrict__ qb,
                                                 u16* __restrict__ kbf,
                                                 u16* __restrict__ vtb) {
    int b = blockIdx.z;
    int n0 = blockIdx.x * 32;
    int w = threadIdx.x >> 6, lane = threadIdx.x & 63;
    int c = lane & 15, u = lane >> 4;
    int o0 = blockIdx.y * 64 + w * 16;
    const f32x4 z = {0.f, 0.f, 0.f, 0.f};
    short8 af0 = *(const short8*)&wbf[(o0 + c) * 128 +  0 + u * 8];
    short8 af1 = *(const short8*)&wbf[(o0 + c) * 128 + 32 + u * 8];
    short8 af2 = *(const short8*)&wbf[(o0 + c) * 128 + 64 + u * 8];
    short8 af3 = *(const short8*)&wbf[(o0 + c) * 128 + 96 + u * 8];
    int tq = o0 >> 7, h = (o0 >> 5) & 3, d0 = (o0 & 31) + u * 4;
    size_t bh = (size_t)b * NHD + h;
    const u16* xb = &xT[(size_t)b * NN * 128];
#pragma unroll
    for (int nt = 0; nt < 2; ++nt) {
        int n = n0 + nt * 16 + c;
        f32x4 acc = z;
        acc = __builtin_amdgcn_mfma_f32_16x16x32_bf16(af0,
            *(const short8*)&xb[(size_t)n * 128 +  0 + u * 8], acc, 0, 0, 0);
        acc = __builtin_amdgcn_mfma_f32_16x16x32_bf16(af1,
            *(const short8*)&xb[(size_t)n * 128 + 32 + u * 8], acc, 0, 0, 0);
        acc = __builtin_amdgcn_mfma_f32_16x16x32_bf16(af2,
            *(const short8*)&xb[(size_t)n * 128 + 64 + u * 8], acc, 0, 0, 0);
        acc = __builtin_amdgcn_mfma_f32_16x16x32_bf16(af3,
            *(const short8*)&xb[(size_t)n * 128 + 96 + u * 8], acc, 0, 0, 0);
        if (tq == 0) {
            *(short4v*)&qb[(bh * NN + n) * HD + d0] =
                pack4(acc[0] * QSC, acc[1] * QSC, acc[2] * QSC, acc[3] * QSC);
        } else if (tq == 1) {
            *(short4v*)&kbf[(bh * NKP + n) * HD + d0] =
                pack4(acc[0], acc[1], acc[2], acc[3]);
        } else {
            int tile = n >> 7, kt2 = n & 127;
            int sub = kt2 >> 4, uu = (kt2 >> 2) & 3, jj = n & 3;
            size_t vb0 = ((size_t)bh * NTILE + tile) * 4096 + sub * 512 + uu * 128 + jj;
#pragma unroll
            for (int r = 0; r < 4; ++r)
                vtb[vb0 + (d0 + r) * 4] = bfb(acc[r]);
        }
    }
}

// ---------------------------------------------------------------------------
// agent tokens: 8x8 block mean -> agb bf16 [bh][64(pad)][32], agT [bh][32][64].
__global__ void k_agent(const float* __restrict__ xf, u16* __restrict__ agb,
                        u16* __restrict__ agT) {
    int idx = blockIdx.x * 256 + threadIdx.x;
    const int NPOOL = NB * NC * NA;   // 12544
    if (idx < NPOOL) {
        int b = idx / (NC * NA);
        int r = idx % (NC * NA);
        int c = r / NA;
        int a = r % NA;
        int ai = a / 7, aj = a % 7;
        const float* base = xf + (b * NC + c) * NN + ai * 8 * 56 + aj * 8;
        float s = 0.f;
#pragma unroll
        for (int uu = 0; uu < 8; ++uu) {
            float4 v0 = *(const float4*)&base[uu * 56];
            float4 v1 = *(const float4*)&base[uu * 56 + 4];
            s += v0.x + v0.y + v0.z + v0.w + v1.x + v1.y + v1.z + v1.w;
        }
        int h = c >> 5, d = c & 31;
        int bh = b * NHD + h;
        u16 val = bfb(s * (1.f / 64.f));
        agb[bh * 2048 + a * 32 + d] = val;
        agT[bh * 2048 + d * 64 + a] = val;
    } else {
        int j = idx - NPOOL;
        if (j < 3840) {
            int bh = j / 480, rem = j % 480;
            int a = 49 + rem / 32, d = rem % 32;
            agb[bh * 2048 + a * 32 + d] = 0;
        } else if (j < 7680) {
            j -= 3840;
            int bh = j / 480, rem = j % 480;
            int a = 49 + rem / 32, d = rem % 32;
            agT[bh * 2048 + d * 64 + a] = 0;
        }
    }
}

// ---------------------------------------------------------------------------
// stage 1 via MFMA (S^T layout identity). grid (49,4,NB) x 256.
__global__ __launch_bounds__(256, 4) void k_stage1_2(const u16* __restrict__ qb,
                                                     const u16* __restrict__ agb,
                                                     const u16* __restrict__ agT,
                                                     u16* __restrict__ qcb) {
    int b = blockIdx.z, h = blockIdx.y;
    int w = threadIdx.x >> 6, lane = threadIdx.x & 63;
    int c = lane & 15, u = lane >> 4;
    int q0 = blockIdx.x * 64 + w * 16;
    size_t bh = (size_t)b * NHD + h;
    const u16* aB = agb + bh * 2048;
    const u16* aT = agT + bh * 2048;
    const f32x4 z = {0.f, 0.f, 0.f, 0.f};
    short8 qf = *(const short8*)&qb[(bh * NN + q0 + c) * HD + u * 8];
    f32x4 st[4];
#pragma unroll
    for (int t = 0; t < 4; ++t) {
        short8 afr = *(const short8*)&aB[(t * 16 + c) * 32 + u * 8];
        st[t] = __builtin_amdgcn_mfma_f32_16x16x32_bf16(afr, qf, z, 0, 0, 0);
    }
    float e[4][4];
    float lsum = 0.f;
#pragma unroll
    for (int t = 0; t < 4; ++t)
#pragma unroll
        for (int r = 0; r < 4; ++r) {
            float v = __builtin_amdgcn_exp2f(st[t][r]);
            if (t == 3 && !(u == 0 && r == 0)) v = 0.f;   // agents >= 49
            e[t][r] = v;
            lsum += v;
        }
    lsum += __shfl_xor(lsum, 16);
    lsum += __shfl_xor(lsum, 32);
    float linv = 1.f / lsum;
    f32x4 qlo = z, qhi = z;
#pragma unroll
    for (int t = 0; t < 4; ++t) {
        short4v pf = pack4(e[t][0] * linv, e[t][1] * linv, e[t][2] * linv, e[t][3] * linv);
        short4v alo = *(const short4v*)&aT[c * 64 + t * 16 + u * 4];
        short4v ahi = *(const short4v*)&aT[(c + 16) * 64 + t * 16 + u * 4];
        qlo = __builtin_amdgcn_mfma_f32_16x16x16bf16_1k(alo, pf, qlo, 0, 0, 0);
        qhi = __builtin_amdgcn_mfma_f32_16x16x16bf16_1k(ahi, pf, qhi, 0, 0, 0);
    }
    u16* dst = &qcb[(bh * NN + q0 + c) * HD];
    *(short4v*)&dst[u * 4]      = pack4(qlo[0] * QSC, qlo[1] * QSC, qlo[2] * QSC, qlo[3] * QSC);
    *(short4v*)&dst[16 + u * 4] = pack4(qhi[0] * QSC, qhi[1] * QSC, qhi[2] * QSC, qhi[3] * QSC);
}

// ---------------------------------------------------------------------------
// stage 2 flash: LDS double-buffer via global_load_lds (no result registers
// to rematerialize; K/V shared by all 4 waves). Wave = 32 q-rows (2 frags),
// tile = 128 keys. Loop: sync; stage(t+1); compute(t) -> staging latency
// hidden behind a full tile of compute. V pre-fragmented so ds_read_b64 is
// bank-conflict-free (bank = 2c). grid (25, NHD*NSPLIT, NB) x 256.
__global__ __launch_bounds__(256, 3) void k_flash4(const u16* __restrict__ qc,
                                                   const u16* __restrict__ kb,
                                                   const u16* __restrict__ vt,
                                                   float* __restrict__ op,
                                                   float* __restrict__ lp) {
    __shared__ __align__(16) u16 Ks[2][4096];
    __shared__ __align__(16) u16 Vs[2][4096];
    int b = blockIdx.z;
    int h = blockIdx.y & 3;
    int s = blockIdx.y >> 2;
    int w = threadIdx.x >> 6, lane = threadIdx.x & 63;
    int c = lane & 15, u = lane >> 4;
    int qa = blockIdx.x * 128 + w * 32;
    int qbr = qa + 16;
    if (qa  > NN - 16) qa  = NN - 16;   // tail clamp: duplicate rows, same values
    if (qbr > NN - 16) qbr = NN - 16;
    size_t bh = (size_t)b * NHD + h;
    const u16* kg = kb + bh * (size_t)NKP * HD;      // tile t at +t*4096
    const u16* vg = vt + bh * (size_t)NTILE * 4096;  // tile t at +t*4096
    short8 qfA = *(const short8*)(qc + (bh * NN + qa  + c) * HD + u * 8);
    short8 qfB = *(const short8*)(qc + (bh * NN + qbr + c) * HD + u * 8);
    const f32x4 z = {0.f, 0.f, 0.f, 0.f};
    f32x4 oA0 = z, oA1 = z, oB0 = z, oB1 = z;
    float lA = 0.f, lB = 0.f;
    int t0 = (s * NTILE) / NSPLIT, t1 = ((s + 1) * NTILE) / NSPLIT;
    stage8k(kg + (size_t)t0 * 4096, &Ks[0][0], w, lane);
    stage8k(vg + (size_t)t0 * 4096, &Vs[0][0], w, lane);
#pragma unroll 1
    for (int t = t0; t < t1; ++t) {
        int buf = (t - t0) & 1;
        __syncthreads();                  // drains stage(t); waves synced
        if (t + 1 < t1) {
            stage8k(kg + (size_t)(t + 1) * 4096, &Ks[buf ^ 1][0], w, lane);
            stage8k(vg + (size_t)(t + 1) * 4096, &Vs[buf ^ 1][0], w, lane);
        }
        const u16* kp = &Ks[buf][0];
        const u16* vp = &Vs[buf][0];
        int kk = t * 128;
        bool tail = (kk + 128 > NN);
#pragma unroll
        for (int sub = 0; sub < 8; ++sub) {
            short8 kf = *(const short8*)(kp + sub * 512 + c * 32 + u * 8);
            f32x4 sA = __builtin_amdgcn_mfma_f32_16x16x32_bf16(kf, qfA, z, 0, 0, 0);
            f32x4 sB = __builtin_amdgcn_mfma_f32_16x16x32_bf16(kf, qfB, z, 0, 0, 0);
            float eA[4], eB[4];
#pragma unroll
            for (int r = 0; r < 4; ++r) {
                eA[r] = __builtin_amdgcn_exp2f(sA[r]);
                eB[r] = __builtin_amdgcn_exp2f(sB[r]);
            }
            if (tail) {
#pragma unroll
                for (int r = 0; r < 4; ++r)
                    if (kk + sub * 16 + u * 4 + r >= NN) { eA[r] = 0.f; eB[r] = 0.f; }
            }
            lA += (eA[0] + eA[1]) + (eA[2] + eA[3]);
            lB += (eB[0] + eB[1]) + (eB[2] + eB[3]);
            short4v pA = pack4(eA[0], eA[1], eA[2], eA[3]);
            short4v pB = pack4(eB[0], eB[1], eB[2], eB[3]);
            short4v va = *(const short4v*)(vp + sub * 512 + u * 128 + c * 4);
            short4v vb = *(const short4v*)(vp + sub * 512 + u * 128 + (c + 16) * 4);
            oA0 = __builtin_amdgcn_mfma_f32_16x16x16bf16_1k(va, pA, oA0, 0, 0, 0);
            oA1 = __builtin_amdgcn_mfma_f32_16x16x16bf16_1k(vb, pA, oA1, 0, 0, 0);
            oB0 = __builtin_amdgcn_mfma_f32_16x16x16bf16_1k(va, pB, oB0, 0, 0, 0);
            oB1 = __builtin_amdgcn_mfma_f32_16x16x16bf16_1k(vb, pB, oB1, 0, 0, 0);
        }
    }
    lA += __shfl_xor(lA, 16); lA += __shfl_xor(lA, 32);
    lB += __shfl_xor(lB, 16); lB += __shfl_xor(lB, 32);
    float* oba = op + (((size_t)(s * NB + b)) * NN + qa + c) * NC + h * HD;
    *(f32x4*)&oba[u * 4]      = oA0;
    *(f32x4*)&oba[16 + u * 4] = oA1;
    float* obb = op + (((size_t)(s * NB + b)) * NN + qbr + c) * NC + h * HD;
    *(f32x4*)&obb[u * 4]      = oB0;
    *(f32x4*)&obb[16 + u * 4] = oB1;
    if (u == 0) {
        lp[(((size_t)(s * NB + b)) * NHD + h) * NN + qa  + c] = lA;
        lp[(((size_t)(s * NB + b)) * NHD + h) * NN + qbr + c] = lB;
    }
}

// ---------------------------------------------------------------------------
// combine partials + normalize + proj + LN + NCHW store. 2 rows per block
// (halves weight re-reads). grid NB*NN/2 x 128.
__global__ __launch_bounds__(128) void k_proj_ln(const float* __restrict__ op,
                                                 const float* __restrict__ lp,
                                                 const float* __restrict__ wpt,
                                                 const float* __restrict__ bgb,
                                                 void* __restrict__ out,
                                                 const int* __restrict__ flag) {
    __shared__ float rowA[NC], rowB[NC];
    __shared__ float red[8];
    int bnA = blockIdx.x * 2, bnB = bnA + 1;
    int bA = bnA / NN, nA = bnA % NN;
    int bB = bnB / NN, nB = bnB % NN;
    int o = threadIdx.x;
    int hh = o >> 5;
    float lsA = 0.f, ovA = 0.f, lsB = 0.f, ovB = 0.f;
#pragma unroll
    for (int s = 0; s < NSPLIT; ++s) {
        lsA += lp[(((size_t)(s * NB + bA)) * NHD + hh) * NN + nA];
        ovA += op[(((size_t)(s * NB + bA)) * NN + nA) * NC + o];
        lsB += lp[(((size_t)(s * NB + bB)) * NHD + hh) * NN + nB];
        ovB += op[(((size_t)(s * NB + bB)) * NN + nB) * NC + o];
    }
    rowA[o] = ovA / lsA;
    rowB[o] = ovB / lsB;
    __syncthreads();
    float aA = bgb[o], aB = bgb[o];
#pragma unroll 4
    for (int cc = 0; cc < NC; ++cc) {
        float wv = wpt[cc * NC + o];
        aA += rowA[cc] * wv;
        aB += rowB[cc] * wv;
    }
    float s1A = aA, s2A = aA * aA, s1B = aB, s2B = aB * aB;
#pragma unroll
    for (int off = 32; off; off >>= 1) {
        s1A += __shfl_xor(s1A, off); s2A += __shfl_xor(s2A, off);
        s1B += __shfl_xor(s1B, off); s2B += __shfl_xor(s2B, off);
    }
    if ((o & 63) == 0) {
        int wv2 = (o >> 6) * 4;
        red[wv2] = s1A; red[wv2 + 1] = s2A; red[wv2 + 2] = s1B; red[wv2 + 3] = s2B;
    }
    __syncthreads();
    float muA = (red[0] + red[4]) * (1.f / NC);
    float exA = (red[1] + red[5]) * (1.f / NC);
    float muB = (red[2] + red[6]) * (1.f / NC);
    float exB = (red[3] + red[7]) * (1.f / NC);
    float rsA = rsqrtf(exA - muA * muA + 1e-5f);
    float rsB = rsqrtf(exB - muB * muB + 1e-5f);
    float g = bgb[128 + o], be = bgb[256 + o];
    float valA = (aA - muA) * rsA * g + be;
    float valB = (aB - muB) * rsB * g + be;
    size_t oiA = ((size_t)(bA * NC + o)) * NN + nA;
    size_t oiB = ((size_t)(bB * NC + o)) * NN + nB;
    if (*flag) {
        ((__hip_bfloat16*)out)[oiA] = __float2bfloat16(valA);
        ((__hip_bfloat16*)out)[oiB] = __float2bfloat16(valB);
    } else {
        ((float*)out)[oiA] = valA;
        ((float*)out)[oiB] = valB;
    }
}

// ---------------------------------------------------------------------------
extern "C" void kernel_launch(void* const* d_in, const int* in_sizes, int n_in,
                              void* d_out, int out_size, void* d_ws, size_t ws_size,
                              hipStream_t stream) {
    const void* x_raw  = d_in[0];
    const void* wq_raw = d_in[1];
    const void* wp_raw = d_in[2];
    const void* bp_raw = d_in[3];
    const void* lg_raw = d_in[4];
    const void* lb_raw = d_in[5];

    float* ws   = (float*)d_ws;
    int*   flag = (int*)d_ws;
    float* xf   = ws + 16;                              // 802816
    float* wpt  = xf + (size_t)NB * NC * NN;            // 16384
    float* bgb  = wpt + NC * NC;                        // 512
    float* op   = bgb + 512;                            // 4*2*3136*128
    float* lp   = op + (size_t)NSPLIT * NB * NN * NC;   // 4*2*4*3136
    u16*   xT   = (u16*)(lp + (size_t)NSPLIT * NB * NHD * NN);
    u16*   wbf  = xT + (size_t)NB * NN * NC;            // 49152
    u16*   qb   = wbf + 3 * NC * NC;                    // 802816
    u16*   kbf  = qb + (size_t)NB * NHD * NN * HD;      // 819200 (padded keys)
    u16*   vtb  = kbf + (size_t)NB * NHD * NKP * HD;    // 819200 (fragmented)
    u16*   qcb  = vtb + (size_t)NB * NHD * NTILE * 4096;
    u16*   agb  = qcb + (size_t)NB * NHD * NN * HD;     // 16384
    u16*   agT  = agb + NB * NHD * 64 * 32;             // 16384
    // total ~24.9 MB

    k_detect<<<1, 256, 0, stream>>>((const u16*)x_raw, flag);
    k_conv_x<<<dim3(NN / 16, NB), 256, 0, stream>>>(x_raw, xf, xT, flag);
    k_conv_w<<<258, 256, 0, stream>>>(wq_raw, wp_raw, bp_raw, lg_raw, lb_raw,
                                      wbf, wpt, bgb, flag);
    k_qkv2<<<dim3(NN / 32, 6, NB), 256, 0, stream>>>(xT, wbf, qb, kbf, vtb);
    k_agent<<<79, 256, 0, stream>>>(xf, agb, agT);
    k_stage1_2<<<dim3(NN / 64, NHD, NB), 256, 0, stream>>>(qb, agb, agT, qcb);
    k_flash4<<<dim3(25, NHD * NSPLIT, NB), 256, 0, stream>>>(qcb, kbf, vtb, op, lp);
    k_proj_ln<<<NB * NN / 2, 128, 0, stream>>>(op, lp, wpt, bgb, d_out, flag);
}

// Round 6
// 124.023 us; speedup vs baseline: 1.7752x; 1.1392x over previous
//
#include <hip/hip_runtime.h>
#include <hip/hip_bf16.h>
#include <stdint.h>

typedef unsigned short u16;
typedef __attribute__((ext_vector_type(8))) short short8;   // 8 bf16 (4 VGPRs)
typedef __attribute__((ext_vector_type(4))) short short4v;  // 4 bf16 (2 VGPRs)
typedef __attribute__((ext_vector_type(4))) float f32x4;    // MFMA C/D

#define NB 2
#define NC 128
#define NHD 4      // heads
#define HD 32      // head dim
#define NN 3136    // H*W
#define NA 49      // agent tokens
#define NSPLIT 4   // flash K-split
#define NKP 3200   // padded key count (25 tiles of 128)
#define NTILE 25
#define SCALE 0.17677669529663687f  // 1/sqrt(32)
#define LOG2E 1.4426950408889634f
#define QSC (SCALE * LOG2E)

__device__ inline u16 bfb(float f) {
    __hip_bfloat16 h = __float2bfloat16(f);
    return *(u16*)&h;
}
__device__ inline float b2f(u16 w) {
    return __uint_as_float(((uint32_t)w) << 16);
}
__device__ inline short4v pack4(float a, float b, float c, float d) {
    union { short4v s; __hip_bfloat162 h[2]; } u;
    u.h[0] = __float22bfloat162_rn(make_float2(a, b));
    u.h[1] = __float22bfloat162_rn(make_float2(c, d));
    return u.s;
}
__device__ inline float ldf(const void* p, size_t i, int f) {
    return f ? b2f(((const u16*)p)[i]) : ((const float*)p)[i];
}
// async global->LDS, 16B per lane; lds dest = uniform base + lane*16
__device__ inline void gld16(const u16* g, u16* l) {
    __builtin_amdgcn_global_load_lds(
        (__attribute__((address_space(1))) void*)(g),
        (__attribute__((address_space(3))) void*)(l), 16, 0, 0);
}
__device__ inline void stage8k(const u16* g, u16* lds, int w, int lane) {
    gld16(g + (size_t)(w * 64 + lane) * 8,       lds + (size_t)w * 512);
    gld16(g + (size_t)(256 + w * 64 + lane) * 8, lds + 2048 + (size_t)w * 512);
}

// ---------------------------------------------------------------------------
__global__ void k_detect(const u16* __restrict__ raw, int* __restrict__ flag) {
    __shared__ int cnt;
    if (threadIdx.x == 0) cnt = 0;
    __syncthreads();
    u16 w = raw[threadIdx.x * 97];
    float f = b2f(w);
    float a = fabsf(f);
    if (a >= 1e-4f && a <= 100.0f) atomicAdd(&cnt, 1);
    __syncthreads();
    if (threadIdx.x == 0) *flag = (cnt >= 230) ? 1 : 0;
}

// ---------------------------------------------------------------------------
// fused prep: [0,392) x -> xT bf16 [b][n][c] (LDS tile transpose);
// [392,584) wqkv -> wbf bf16; [584,648) wproj -> wpb bf16 [o][c];
// [648,650) biases -> bgb; [650,729) agent 8x8 pool from RAW x -> agb/agT.
__global__ __launch_bounds__(256) void k_prep(const void* __restrict__ xr,
                                              const void* __restrict__ wq,
                                              const void* __restrict__ wp,
                                              const void* __restrict__ bp,
                                              const void* __restrict__ g,
                                              const void* __restrict__ bb,
                                              u16* __restrict__ xT,
                                              u16* __restrict__ wbf,
                                              u16* __restrict__ wpb,
                                              float* __restrict__ bgb,
                                              u16* __restrict__ agb,
                                              u16* __restrict__ agT,
                                              const int* __restrict__ flag) {
    __shared__ u16 tile[128][18];
    int bx = blockIdx.x, t = threadIdx.x;
    int f = *flag;
    if (bx < 392) {
        int b = bx / 196;
        int n0 = (bx % 196) * 16;
        int c = t >> 1, nh = (t & 1) * 8;
        size_t src = ((size_t)(b * 128 + c)) * NN + n0 + nh;
#pragma unroll
        for (int i = 0; i < 8; ++i) tile[c][nh + i] = bfb(ldf(xr, src + i, f));
        __syncthreads();
        int n = t >> 4, c0 = (t & 15) * 8;
        short8 o;
#pragma unroll
        for (int i = 0; i < 8; ++i) o[i] = (short)tile[c0 + i][n];
        *(short8*)&xT[((size_t)b * NN + n0 + n) * 128 + c0] = o;
    } else if (bx < 584) {
        int i = (bx - 392) * 256 + t;
        wbf[i] = bfb(ldf(wq, i, f));
    } else if (bx < 648) {
        int i = (bx - 584) * 256 + t;
        wpb[i] = bfb(ldf(wp, i, f));
    } else if (bx < 650) {
        int i = (bx - 648) * 256 + t;
        if (i < 128)      bgb[i] = ldf(bp, i, f);
        else if (i < 256) bgb[i] = ldf(g, i - 128, f);
        else if (i < 384) bgb[i] = ldf(bb, i - 256, f);
    } else {
        int idx = (bx - 650) * 256 + t;
        const int NPOOL = NB * NC * NA;   // 12544
        if (idx < NPOOL) {
            int b = idx / (NC * NA);
            int r = idx % (NC * NA);
            int c = r / NA;
            int a = r % NA;
            int ai = a / 7, aj = a % 7;
            size_t base = ((size_t)(b * NC + c)) * NN + ai * 8 * 56 + aj * 8;
            float s = 0.f;
            if (f) {
                const u16* xp = (const u16*)xr + base;
#pragma unroll
                for (int uu = 0; uu < 8; ++uu) {
                    ushort4 a0 = *(const ushort4*)&xp[uu * 56];
                    ushort4 a1 = *(const ushort4*)&xp[uu * 56 + 4];
                    s += b2f(a0.x) + b2f(a0.y) + b2f(a0.z) + b2f(a0.w)
                       + b2f(a1.x) + b2f(a1.y) + b2f(a1.z) + b2f(a1.w);
                }
            } else {
                const float* xp = (const float*)xr + base;
#pragma unroll
                for (int uu = 0; uu < 8; ++uu) {
                    float4 v0 = *(const float4*)&xp[uu * 56];
                    float4 v1 = *(const float4*)&xp[uu * 56 + 4];
                    s += v0.x + v0.y + v0.z + v0.w + v1.x + v1.y + v1.z + v1.w;
                }
            }
            int h = c >> 5, d = c & 31;
            int bh = b * NHD + h;
            u16 val = bfb(s * (1.f / 64.f));
            agb[bh * 2048 + a * 32 + d] = val;
            agT[bh * 2048 + d * 64 + a] = val;
        } else {
            int j = idx - NPOOL;
            if (j < 3840) {
                int bh = j / 480, rem = j % 480;
                int a = 49 + rem / 32, d = rem % 32;
                agb[bh * 2048 + a * 32 + d] = 0;
            } else if (j < 7680) {
                j -= 3840;
                int bh = j / 480, rem = j % 480;
                int a = 49 + rem / 32, d = rem % 32;
                agT[bh * 2048 + d * 64 + a] = 0;
            }
        }
    }
}

// ---------------------------------------------------------------------------
// QKV via bf16 MFMA. Wave: 16 o x 64 n (4 n-tiles, A held). grid (49,6,NB).
__global__ __launch_bounds__(256, 4) void k_qkv2(const u16* __restrict__ xT,
                                                 const u16* __restrict__ wbf,
                                                 u16* __restrict__ qb,
                                                 u16* __restrict__ kbf,
                                                 u16* __restrict__ vtb) {
    int b = blockIdx.z;
    int n0 = blockIdx.x * 64;
    int w = threadIdx.x >> 6, lane = threadIdx.x & 63;
    int c = lane & 15, u = lane >> 4;
    int o0 = blockIdx.y * 64 + w * 16;
    const f32x4 z = {0.f, 0.f, 0.f, 0.f};
    short8 af0 = *(const short8*)&wbf[(o0 + c) * 128 +  0 + u * 8];
    short8 af1 = *(const short8*)&wbf[(o0 + c) * 128 + 32 + u * 8];
    short8 af2 = *(const short8*)&wbf[(o0 + c) * 128 + 64 + u * 8];
    short8 af3 = *(const short8*)&wbf[(o0 + c) * 128 + 96 + u * 8];
    int tq = o0 >> 7, h = (o0 >> 5) & 3, d0 = (o0 & 31) + u * 4;
    size_t bh = (size_t)b * NHD + h;
    const u16* xb = &xT[(size_t)b * NN * 128];
#pragma unroll
    for (int nt = 0; nt < 4; ++nt) {
        int n = n0 + nt * 16 + c;
        f32x4 acc = z;
        acc = __builtin_amdgcn_mfma_f32_16x16x32_bf16(af0,
            *(const short8*)&xb[(size_t)n * 128 +  0 + u * 8], acc, 0, 0, 0);
        acc = __builtin_amdgcn_mfma_f32_16x16x32_bf16(af1,
            *(const short8*)&xb[(size_t)n * 128 + 32 + u * 8], acc, 0, 0, 0);
        acc = __builtin_amdgcn_mfma_f32_16x16x32_bf16(af2,
            *(const short8*)&xb[(size_t)n * 128 + 64 + u * 8], acc, 0, 0, 0);
        acc = __builtin_amdgcn_mfma_f32_16x16x32_bf16(af3,
            *(const short8*)&xb[(size_t)n * 128 + 96 + u * 8], acc, 0, 0, 0);
        if (tq == 0) {
            *(short4v*)&qb[(bh * NN + n) * HD + d0] =
                pack4(acc[0] * QSC, acc[1] * QSC, acc[2] * QSC, acc[3] * QSC);
        } else if (tq == 1) {
            *(short4v*)&kbf[(bh * NKP + n) * HD + d0] =
                pack4(acc[0], acc[1], acc[2], acc[3]);
        } else {
            int tile = n >> 7, kt2 = n & 127;
            int sub = kt2 >> 4, uu = (kt2 >> 2) & 3, jj = n & 3;
            size_t vb0 = ((size_t)bh * NTILE + tile) * 4096 + sub * 512 + uu * 128 + jj;
#pragma unroll
            for (int r = 0; r < 4; ++r)
                vtb[vb0 + (d0 + r) * 4] = bfb(acc[r]);
        }
    }
}

// ---------------------------------------------------------------------------
// stage 1 via MFMA (S^T layout identity). grid (49,4,NB) x 256.
__global__ __launch_bounds__(256, 4) void k_stage1_2(const u16* __restrict__ qb,
                                                     const u16* __restrict__ agb,
                                                     const u16* __restrict__ agT,
                                                     u16* __restrict__ qcb) {
    int b = blockIdx.z, h = blockIdx.y;
    int w = threadIdx.x >> 6, lane = threadIdx.x & 63;
    int c = lane & 15, u = lane >> 4;
    int q0 = blockIdx.x * 64 + w * 16;
    size_t bh = (size_t)b * NHD + h;
    const u16* aB = agb + bh * 2048;
    const u16* aT = agT + bh * 2048;
    const f32x4 z = {0.f, 0.f, 0.f, 0.f};
    short8 qf = *(const short8*)&qb[(bh * NN + q0 + c) * HD + u * 8];
    f32x4 st[4];
#pragma unroll
    for (int t = 0; t < 4; ++t) {
        short8 afr = *(const short8*)&aB[(t * 16 + c) * 32 + u * 8];
        st[t] = __builtin_amdgcn_mfma_f32_16x16x32_bf16(afr, qf, z, 0, 0, 0);
    }
    float e[4][4];
    float lsum = 0.f;
#pragma unroll
    for (int t = 0; t < 4; ++t)
#pragma unroll
        for (int r = 0; r < 4; ++r) {
            float v = __builtin_amdgcn_exp2f(st[t][r]);
            if (t == 3 && !(u == 0 && r == 0)) v = 0.f;   // agents >= 49
            e[t][r] = v;
            lsum += v;
        }
    lsum += __shfl_xor(lsum, 16);
    lsum += __shfl_xor(lsum, 32);
    float linv = 1.f / lsum;
    f32x4 qlo = z, qhi = z;
#pragma unroll
    for (int t = 0; t < 4; ++t) {
        short4v pf = pack4(e[t][0] * linv, e[t][1] * linv, e[t][2] * linv, e[t][3] * linv);
        short4v alo = *(const short4v*)&aT[c * 64 + t * 16 + u * 4];
        short4v ahi = *(const short4v*)&aT[(c + 16) * 64 + t * 16 + u * 4];
        qlo = __builtin_amdgcn_mfma_f32_16x16x16bf16_1k(alo, pf, qlo, 0, 0, 0);
        qhi = __builtin_amdgcn_mfma_f32_16x16x16bf16_1k(ahi, pf, qhi, 0, 0, 0);
    }
    u16* dst = &qcb[(bh * NN + q0 + c) * HD];
    *(short4v*)&dst[u * 4]      = pack4(qlo[0] * QSC, qlo[1] * QSC, qlo[2] * QSC, qlo[3] * QSC);
    *(short4v*)&dst[16 + u * 4] = pack4(qhi[0] * QSC, qhi[1] * QSC, qhi[2] * QSC, qhi[3] * QSC);
}

// ---------------------------------------------------------------------------
// stage 2 flash: LDS double-buffer via global_load_lds. Wave = 32 q-rows,
// tile = 128 keys. grid (25, NHD*NSPLIT, NB) x 256.
__global__ __launch_bounds__(256, 3) void k_flash4(const u16* __restrict__ qc,
                                                   const u16* __restrict__ kb,
                                                   const u16* __restrict__ vt,
                                                   float* __restrict__ op,
                                                   float* __restrict__ lp) {
    __shared__ __align__(16) u16 Ks[2][4096];
    __shared__ __align__(16) u16 Vs[2][4096];
    int b = blockIdx.z;
    int h = blockIdx.y & 3;
    int s = blockIdx.y >> 2;
    int w = threadIdx.x >> 6, lane = threadIdx.x & 63;
    int c = lane & 15, u = lane >> 4;
    int qa = blockIdx.x * 128 + w * 32;
    int qbr = qa + 16;
    if (qa  > NN - 16) qa  = NN - 16;
    if (qbr > NN - 16) qbr = NN - 16;
    size_t bh = (size_t)b * NHD + h;
    const u16* kg = kb + bh * (size_t)NKP * HD;
    const u16* vg = vt + bh * (size_t)NTILE * 4096;
    short8 qfA = *(const short8*)(qc + (bh * NN + qa  + c) * HD + u * 8);
    short8 qfB = *(const short8*)(qc + (bh * NN + qbr + c) * HD + u * 8);
    const f32x4 z = {0.f, 0.f, 0.f, 0.f};
    f32x4 oA0 = z, oA1 = z, oB0 = z, oB1 = z;
    float lA = 0.f, lB = 0.f;
    int t0 = (s * NTILE) / NSPLIT, t1 = ((s + 1) * NTILE) / NSPLIT;
    stage8k(kg + (size_t)t0 * 4096, &Ks[0][0], w, lane);
    stage8k(vg + (size_t)t0 * 4096, &Vs[0][0], w, lane);
#pragma unroll 1
    for (int t = t0; t < t1; ++t) {
        int buf = (t - t0) & 1;
        __syncthreads();
        if (t + 1 < t1) {
            stage8k(kg + (size_t)(t + 1) * 4096, &Ks[buf ^ 1][0], w, lane);
            stage8k(vg + (size_t)(t + 1) * 4096, &Vs[buf ^ 1][0], w, lane);
        }
        const u16* kp = &Ks[buf][0];
        const u16* vp = &Vs[buf][0];
        int kk = t * 128;
        bool tail = (kk + 128 > NN);
#pragma unroll
        for (int sub = 0; sub < 8; ++sub) {
            short8 kf = *(const short8*)(kp + sub * 512 + c * 32 + u * 8);
            f32x4 sA = __builtin_amdgcn_mfma_f32_16x16x32_bf16(kf, qfA, z, 0, 0, 0);
            f32x4 sB = __builtin_amdgcn_mfma_f32_16x16x32_bf16(kf, qfB, z, 0, 0, 0);
            float eA[4], eB[4];
#pragma unroll
            for (int r = 0; r < 4; ++r) {
                eA[r] = __builtin_amdgcn_exp2f(sA[r]);
                eB[r] = __builtin_amdgcn_exp2f(sB[r]);
            }
            if (tail) {
#pragma unroll
                for (int r = 0; r < 4; ++r)
                    if (kk + sub * 16 + u * 4 + r >= NN) { eA[r] = 0.f; eB[r] = 0.f; }
            }
            lA += (eA[0] + eA[1]) + (eA[2] + eA[3]);
            lB += (eB[0] + eB[1]) + (eB[2] + eB[3]);
            short4v pA = pack4(eA[0], eA[1], eA[2], eA[3]);
            short4v pB = pack4(eB[0], eB[1], eB[2], eB[3]);
            short4v va = *(const short4v*)(vp + sub * 512 + u * 128 + c * 4);
            short4v vb = *(const short4v*)(vp + sub * 512 + u * 128 + (c + 16) * 4);
            oA0 = __builtin_amdgcn_mfma_f32_16x16x16bf16_1k(va, pA, oA0, 0, 0, 0);
            oA1 = __builtin_amdgcn_mfma_f32_16x16x16bf16_1k(vb, pA, oA1, 0, 0, 0);
            oB0 = __builtin_amdgcn_mfma_f32_16x16x16bf16_1k(va, pB, oB0, 0, 0, 0);
            oB1 = __builtin_amdgcn_mfma_f32_16x16x16bf16_1k(vb, pB, oB1, 0, 0, 0);
        }
    }
    lA += __shfl_xor(lA, 16); lA += __shfl_xor(lA, 32);
    lB += __shfl_xor(lB, 16); lB += __shfl_xor(lB, 32);
    float* oba = op + (((size_t)(s * NB + b)) * NN + qa + c) * NC + h * HD;
    *(f32x4*)&oba[u * 4]      = oA0;
    *(f32x4*)&oba[16 + u * 4] = oA1;
    float* obb = op + (((size_t)(s * NB + b)) * NN + qbr + c) * NC + h * HD;
    *(f32x4*)&obb[u * 4]      = oB0;
    *(f32x4*)&obb[16 + u * 4] = oB1;
    if (u == 0) {
        lp[(((size_t)(s * NB + b)) * NHD + h) * NN + qa  + c] = lA;
        lp[(((size_t)(s * NB + b)) * NHD + h) * NN + qbr + c] = lB;
    }
}

// ---------------------------------------------------------------------------
// proj + LN via MFMA. Block = 16 rows: combine NSPLIT partials -> bf16 A in
// LDS (stride 136) -> 4 waves x (2 o-tiles x 4 K-frags) MFMA vs wpb ->
// per-row LN (4 shuffles + tiny LDS red) -> vectorized NCHW store.
// grid 392 x 256.
__global__ __launch_bounds__(256, 4) void k_proj2(const float* __restrict__ op,
                                                  const float* __restrict__ lp,
                                                  const u16* __restrict__ wpb,
                                                  const float* __restrict__ bgb,
                                                  void* __restrict__ out,
                                                  const int* __restrict__ flag) {
    __shared__ u16 Af[16 * 136];
    __shared__ float red1[4][16], red2[4][16];
    int bx = blockIdx.x;
    int b = bx >= 196;
    int n0 = (bx - b * 196) * 16;
    int t = threadIdx.x;
    {   // combine: thread t -> row t>>4, channels (t&15)*8..+7
        int row = t >> 4, c8 = (t & 15) * 8;
        int n = n0 + row;
        int hh = c8 >> 5;
        float ls = 0.f;
#pragma unroll
        for (int s = 0; s < NSPLIT; ++s)
            ls += lp[(((size_t)(s * NB + b)) * NHD + hh) * NN + n];
        float inv = 1.f / ls;
        float v[8] = {};
#pragma unroll
        for (int s = 0; s < NSPLIT; ++s) {
            const float* src = &op[(((size_t)(s * NB + b)) * NN + n) * NC + c8];
            float4 x0 = *(const float4*)&src[0];
            float4 x1 = *(const float4*)&src[4];
            v[0] += x0.x; v[1] += x0.y; v[2] += x0.z; v[3] += x0.w;
            v[4] += x1.x; v[5] += x1.y; v[6] += x1.z; v[7] += x1.w;
        }
        u16* dst = &Af[row * 136 + c8];
#pragma unroll
        for (int i = 0; i < 8; i += 2) {
            __hip_bfloat162 p = __float22bfloat162_rn(make_float2(v[i] * inv, v[i + 1] * inv));
            *(uint32_t*)&dst[i] = *(uint32_t*)&p;
        }
    }
    __syncthreads();
    int w = t >> 6, lane = t & 63, c = lane & 15, u = lane >> 4;
    int oA = w * 32 + c, oB = w * 32 + 16 + c;
    const f32x4 z = {0.f, 0.f, 0.f, 0.f};
    f32x4 cA = z, cB = z;
#pragma unroll
    for (int kf = 0; kf < 4; ++kf) {
        short8 a  = *(const short8*)&Af[c * 136 + kf * 32 + u * 8];
        short8 bA = *(const short8*)&wpb[(size_t)oA * 128 + kf * 32 + u * 8];
        short8 bB = *(const short8*)&wpb[(size_t)oB * 128 + kf * 32 + u * 8];
        cA = __builtin_amdgcn_mfma_f32_16x16x32_bf16(a, bA, cA, 0, 0, 0);
        cB = __builtin_amdgcn_mfma_f32_16x16x32_bf16(a, bB, cB, 0, 0, 0);
    }
    float bpA = bgb[oA], bpB = bgb[oB];
    float s1[4], s2[4];
#pragma unroll
    for (int r = 0; r < 4; ++r) {
        cA[r] += bpA; cB[r] += bpB;
        s1[r] = cA[r] + cB[r];
        s2[r] = cA[r] * cA[r] + cB[r] * cB[r];
    }
#pragma unroll
    for (int off = 1; off < 16; off <<= 1)
#pragma unroll
        for (int r = 0; r < 4; ++r) {
            s1[r] += __shfl_xor(s1[r], off);
            s2[r] += __shfl_xor(s2[r], off);
        }
    if (c == 0)
#pragma unroll
        for (int r = 0; r < 4; ++r) {
            red1[w][u * 4 + r] = s1[r];
            red2[w][u * 4 + r] = s2[r];
        }
    __syncthreads();
    float gA = bgb[128 + oA], beA = bgb[256 + oA];
    float gB = bgb[128 + oB], beB = bgb[256 + oB];
    float outA[4], outB[4];
#pragma unroll
    for (int r = 0; r < 4; ++r) {
        int row = u * 4 + r;
        float S1 = (red1[0][row] + red1[1][row]) + (red1[2][row] + red1[3][row]);
        float S2 = (red2[0][row] + red2[1][row]) + (red2[2][row] + red2[3][row]);
        float mu = S1 * (1.f / NC);
        float ex = S2 * (1.f / NC);
        float rstd = rsqrtf(ex - mu * mu + 1e-5f);
        outA[r] = (cA[r] - mu) * rstd * gA + beA;
        outB[r] = (cB[r] - mu) * rstd * gB + beB;
    }
    int n = n0 + u * 4;   // 4 consecutive rows per lane
    if (*flag) {
        __hip_bfloat16* ob = (__hip_bfloat16*)out;
        ushort4 sA = make_ushort4(bfb(outA[0]), bfb(outA[1]), bfb(outA[2]), bfb(outA[3]));
        ushort4 sB = make_ushort4(bfb(outB[0]), bfb(outB[1]), bfb(outB[2]), bfb(outB[3]));
        *(ushort4*)&ob[((size_t)(b * NC + oA)) * NN + n] = sA;
        *(ushort4*)&ob[((size_t)(b * NC + oB)) * NN + n] = sB;
    } else {
        float* ob = (float*)out;
        *(float4*)&ob[((size_t)(b * NC + oA)) * NN + n] = make_float4(outA[0], outA[1], outA[2], outA[3]);
        *(float4*)&ob[((size_t)(b * NC + oB)) * NN + n] = make_float4(outB[0], outB[1], outB[2], outB[3]);
    }
}

// ---------------------------------------------------------------------------
extern "C" void kernel_launch(void* const* d_in, const int* in_sizes, int n_in,
                              void* d_out, int out_size, void* d_ws, size_t ws_size,
                              hipStream_t stream) {
    const void* x_raw  = d_in[0];
    const void* wq_raw = d_in[1];
    const void* wp_raw = d_in[2];
    const void* bp_raw = d_in[3];
    const void* lg_raw = d_in[4];
    const void* lb_raw = d_in[5];

    float* ws   = (float*)d_ws;
    int*   flag = (int*)d_ws;
    float* bgb  = ws + 16;                              // 512
    float* op   = bgb + 512;                            // 4*2*3136*128
    float* lp   = op + (size_t)NSPLIT * NB * NN * NC;   // 4*2*4*3136
    u16*   xT   = (u16*)(lp + (size_t)NSPLIT * NB * NHD * NN);
    u16*   wbf  = xT + (size_t)NB * NN * NC;            // 49152
    u16*   wpb  = wbf + 3 * NC * NC;                    // 16384
    u16*   qb   = wpb + NC * NC;                        // 802816
    u16*   kbf  = qb + (size_t)NB * NHD * NN * HD;      // 819200 (padded keys)
    u16*   vtb  = kbf + (size_t)NB * NHD * NKP * HD;    // 819200 (fragmented)
    u16*   qcb  = vtb + (size_t)NB * NHD * NTILE * 4096;
    u16*   agb  = qcb + (size_t)NB * NHD * NN * HD;     // 16384
    u16*   agT  = agb + NB * NHD * 64 * 32;             // 16384
    // total ~21 MB

    k_detect<<<1, 256, 0, stream>>>((const u16*)x_raw, flag);
    k_prep<<<729, 256, 0, stream>>>(x_raw, wq_raw, wp_raw, bp_raw, lg_raw, lb_raw,
                                    xT, wbf, wpb, bgb, agb, agT, flag);
    k_qkv2<<<dim3(NN / 64, 6, NB), 256, 0, stream>>>(xT, wbf, qb, kbf, vtb);
    k_stage1_2<<<dim3(NN / 64, NHD, NB), 256, 0, stream>>>(qb, agb, agT, qcb);
    k_flash4<<<dim3(25, NHD * NSPLIT, NB), 256, 0, stream>>>(qcb, kbf, vtb, op, lp);
    k_proj2<<<392, 256, 0, stream>>>(op, lp, wpb, bgb, d_out, flag);
}

// Round 7
// 119.273 us; speedup vs baseline: 1.8459x; 1.0398x over previous
//
#include <hip/hip_runtime.h>
#include <hip/hip_bf16.h>
#include <stdint.h>

typedef unsigned short u16;
typedef __attribute__((ext_vector_type(8))) short short8;   // 8 bf16 (4 VGPRs)
typedef __attribute__((ext_vector_type(4))) short short4v;  // 4 bf16 (2 VGPRs)
typedef __attribute__((ext_vector_type(4))) float f32x4;    // MFMA C/D

#define NB 2
#define NC 128
#define NHD 4      // heads
#define HD 32      // head dim
#define NN 3136    // H*W
#define NA 49      // agent tokens
#define NSPLIT 4   // flash K-split
#define NKP 3200   // padded key count (25 tiles of 128)
#define NTILE 25
#define SCALE 0.17677669529663687f  // 1/sqrt(32)
#define LOG2E 1.4426950408889634f
#define QSC (SCALE * LOG2E)

__device__ inline u16 bfb(float f) {
    __hip_bfloat16 h = __float2bfloat16(f);
    return *(u16*)&h;
}
__device__ inline float b2f(u16 w) {
    return __uint_as_float(((uint32_t)w) << 16);
}
__device__ inline short4v pack4(float a, float b, float c, float d) {
    union { short4v s; __hip_bfloat162 h[2]; } u;
    u.h[0] = __float22bfloat162_rn(make_float2(a, b));
    u.h[1] = __float22bfloat162_rn(make_float2(c, d));
    return u.s;
}
__device__ inline float ldf(const void* p, size_t i, int f) {
    return f ? b2f(((const u16*)p)[i]) : ((const float*)p)[i];
}
// async global->LDS, 16B per lane; lds dest = uniform base + lane*16
__device__ inline void gld16(const u16* g, u16* l) {
    __builtin_amdgcn_global_load_lds(
        (__attribute__((address_space(1))) void*)(g),
        (__attribute__((address_space(3))) void*)(l), 16, 0, 0);
}
__device__ inline void stage8k(const u16* g, u16* lds, int w, int lane) {
    gld16(g + (size_t)(w * 64 + lane) * 8,       lds + (size_t)w * 512);
    gld16(g + (size_t)(256 + w * 64 + lane) * 8, lds + 2048 + (size_t)w * 512);
}
// per-block dtype detect (deterministic; all 256 threads participate)
__device__ inline int detect_local(const u16* raw, int t) {
    __shared__ int cnt;
    if (t == 0) cnt = 0;
    __syncthreads();
    float a = fabsf(b2f(raw[t * 97]));
    if (a >= 1e-4f && a <= 100.0f) atomicAdd(&cnt, 1);
    __syncthreads();
    return cnt >= 230;
}

// ---------------------------------------------------------------------------
// fused prep: [0,392) x -> xT bf16 [b][n][c]; [392,584) wqkv -> wbf;
// [584,648) wproj -> wpb bf16 [o][c]; [648,650) biases -> bgb (+flag);
// [650,729) agent 8x8 pool from RAW x -> agb/agT. Detect inlined per block.
__global__ __launch_bounds__(256) void k_prep(const void* __restrict__ xr,
                                              const void* __restrict__ wq,
                                              const void* __restrict__ wp,
                                              const void* __restrict__ bp,
                                              const void* __restrict__ g,
                                              const void* __restrict__ bb,
                                              u16* __restrict__ xT,
                                              u16* __restrict__ wbf,
                                              u16* __restrict__ wpb,
                                              float* __restrict__ bgb,
                                              u16* __restrict__ agb,
                                              u16* __restrict__ agT,
                                              int* __restrict__ flagOut) {
    __shared__ u16 tile[128][18];
    int bx = blockIdx.x, t = threadIdx.x;
    int f = detect_local((const u16*)xr, t);
    if (bx < 392) {
        int b = bx / 196;
        int n0 = (bx % 196) * 16;
        int c = t >> 1, nh = (t & 1) * 8;
        size_t src = ((size_t)(b * 128 + c)) * NN + n0 + nh;
#pragma unroll
        for (int i = 0; i < 8; ++i) tile[c][nh + i] = bfb(ldf(xr, src + i, f));
        __syncthreads();
        int n = t >> 4, c0 = (t & 15) * 8;
        short8 o;
#pragma unroll
        for (int i = 0; i < 8; ++i) o[i] = (short)tile[c0 + i][n];
        *(short8*)&xT[((size_t)b * NN + n0 + n) * 128 + c0] = o;
    } else if (bx < 584) {
        int i = (bx - 392) * 256 + t;
        wbf[i] = bfb(ldf(wq, i, f));
    } else if (bx < 648) {
        int i = (bx - 584) * 256 + t;
        wpb[i] = bfb(ldf(wp, i, f));
    } else if (bx < 650) {
        int i = (bx - 648) * 256 + t;
        if (i < 128)      bgb[i] = ldf(bp, i, f);
        else if (i < 256) bgb[i] = ldf(g, i - 128, f);
        else if (i < 384) bgb[i] = ldf(bb, i - 256, f);
        if (bx == 648 && t == 0) *flagOut = f;
    } else {
        int idx = (bx - 650) * 256 + t;
        const int NPOOL = NB * NC * NA;   // 12544
        if (idx < NPOOL) {
            int b = idx / (NC * NA);
            int r = idx % (NC * NA);
            int c = r / NA;
            int a = r % NA;
            int ai = a / 7, aj = a % 7;
            size_t base = ((size_t)(b * NC + c)) * NN + ai * 8 * 56 + aj * 8;
            float s = 0.f;
            if (f) {
                const u16* xp = (const u16*)xr + base;
#pragma unroll
                for (int uu = 0; uu < 8; ++uu) {
                    ushort4 a0 = *(const ushort4*)&xp[uu * 56];
                    ushort4 a1 = *(const ushort4*)&xp[uu * 56 + 4];
                    s += b2f(a0.x) + b2f(a0.y) + b2f(a0.z) + b2f(a0.w)
                       + b2f(a1.x) + b2f(a1.y) + b2f(a1.z) + b2f(a1.w);
                }
            } else {
                const float* xp = (const float*)xr + base;
#pragma unroll
                for (int uu = 0; uu < 8; ++uu) {
                    float4 v0 = *(const float4*)&xp[uu * 56];
                    float4 v1 = *(const float4*)&xp[uu * 56 + 4];
                    s += v0.x + v0.y + v0.z + v0.w + v1.x + v1.y + v1.z + v1.w;
                }
            }
            int h = c >> 5, d = c & 31;
            int bh = b * NHD + h;
            u16 val = bfb(s * (1.f / 64.f));
            agb[bh * 2048 + a * 32 + d] = val;
            agT[bh * 2048 + d * 64 + a] = val;
        } else {
            int j = idx - NPOOL;
            if (j < 3840) {
                int bh = j / 480, rem = j % 480;
                int a = 49 + rem / 32, d = rem % 32;
                agb[bh * 2048 + a * 32 + d] = 0;
            } else if (j < 7680) {
                j -= 3840;
                int bh = j / 480, rem = j % 480;
                int a = 49 + rem / 32, d = rem % 32;
                agT[bh * 2048 + d * 64 + a] = 0;
            }
        }
    }
}

// ---------------------------------------------------------------------------
// QKV + fused stage-1. grid (49, 6, NB) x 256.
// y<2: q (2 heads) -> LDS tile (never hits global), then stage1 for the same
//      64 rows x 2 heads -> qcb (prescaled QSC).
// y 2-3: k -> kbf [bh][NKP][d];  y 4-5: v -> vtb pre-fragmented tiles.
__global__ __launch_bounds__(256, 4) void k_qkv_s1(const u16* __restrict__ xT,
                                                   const u16* __restrict__ wbf,
                                                   const u16* __restrict__ agb,
                                                   const u16* __restrict__ agT,
                                                   u16* __restrict__ kbf,
                                                   u16* __restrict__ vtb,
                                                   u16* __restrict__ qcb) {
    __shared__ u16 qtile[2 * 64 * 40];   // [head][row][32 d], stride 40
    int b = blockIdx.z;
    int n0 = blockIdx.x * 64;
    int w = threadIdx.x >> 6, lane = threadIdx.x & 63;
    int c = lane & 15, u = lane >> 4;
    int o0 = blockIdx.y * 64 + w * 16;
    const f32x4 z = {0.f, 0.f, 0.f, 0.f};
    short8 af0 = *(const short8*)&wbf[(o0 + c) * 128 +  0 + u * 8];
    short8 af1 = *(const short8*)&wbf[(o0 + c) * 128 + 32 + u * 8];
    short8 af2 = *(const short8*)&wbf[(o0 + c) * 128 + 64 + u * 8];
    short8 af3 = *(const short8*)&wbf[(o0 + c) * 128 + 96 + u * 8];
    int tq = o0 >> 7, h = (o0 >> 5) & 3, d0 = (o0 & 31) + u * 4;
    size_t bh = (size_t)b * NHD + h;
    const u16* xb = &xT[(size_t)b * NN * 128];
#pragma unroll
    for (int nt = 0; nt < 4; ++nt) {
        int n = n0 + nt * 16 + c;
        f32x4 acc = z;
        acc = __builtin_amdgcn_mfma_f32_16x16x32_bf16(af0,
            *(const short8*)&xb[(size_t)n * 128 +  0 + u * 8], acc, 0, 0, 0);
        acc = __builtin_amdgcn_mfma_f32_16x16x32_bf16(af1,
            *(const short8*)&xb[(size_t)n * 128 + 32 + u * 8], acc, 0, 0, 0);
        acc = __builtin_amdgcn_mfma_f32_16x16x32_bf16(af2,
            *(const short8*)&xb[(size_t)n * 128 + 64 + u * 8], acc, 0, 0, 0);
        acc = __builtin_amdgcn_mfma_f32_16x16x32_bf16(af3,
            *(const short8*)&xb[(size_t)n * 128 + 96 + u * 8], acc, 0, 0, 0);
        if (tq == 0) {
            int hl = (o0 >> 5) & 1;
            *(short4v*)&qtile[(hl * 64 + nt * 16 + c) * 40 + d0] =
                pack4(acc[0] * QSC, acc[1] * QSC, acc[2] * QSC, acc[3] * QSC);
        } else if (tq == 1) {
            *(short4v*)&kbf[(bh * NKP + n) * HD + d0] =
                pack4(acc[0], acc[1], acc[2], acc[3]);
        } else {
            int tile = n >> 7, kt2 = n & 127;
            int sub = kt2 >> 4, uu = (kt2 >> 2) & 3, jj = n & 3;
            size_t vb0 = ((size_t)bh * NTILE + tile) * 4096 + sub * 512 + uu * 128 + jj;
#pragma unroll
            for (int r = 0; r < 4; ++r)
                vtb[vb0 + (d0 + r) * 4] = bfb(acc[r]);
        }
    }
    if (blockIdx.y < 2) {
        __syncthreads();
        // stage1: 8 tiles (2 heads x 4 row-groups); wave w takes tiles w, w+4
#pragma unroll
        for (int tt = w; tt < 8; tt += 4) {
            int hl2 = tt >> 2, r0 = (tt & 3) * 16;
            int hg = blockIdx.y * 2 + hl2;
            size_t bh2 = (size_t)b * NHD + hg;
            const u16* aB = agb + bh2 * 2048;
            const u16* aT = agT + bh2 * 2048;
            short8 qf = *(const short8*)&qtile[(hl2 * 64 + r0 + c) * 40 + u * 8];
            f32x4 st[4];
#pragma unroll
            for (int t2 = 0; t2 < 4; ++t2) {
                short8 afr = *(const short8*)&aB[(t2 * 16 + c) * 32 + u * 8];
                st[t2] = __builtin_amdgcn_mfma_f32_16x16x32_bf16(afr, qf, z, 0, 0, 0);
            }
            float e[4][4];
            float lsum = 0.f;
#pragma unroll
            for (int t2 = 0; t2 < 4; ++t2)
#pragma unroll
                for (int r = 0; r < 4; ++r) {
                    float v = __builtin_amdgcn_exp2f(st[t2][r]);
                    if (t2 == 3 && !(u == 0 && r == 0)) v = 0.f;   // agents >= 49
                    e[t2][r] = v;
                    lsum += v;
                }
            lsum += __shfl_xor(lsum, 16);
            lsum += __shfl_xor(lsum, 32);
            float linv = 1.f / lsum;
            f32x4 qlo = z, qhi = z;
#pragma unroll
            for (int t2 = 0; t2 < 4; ++t2) {
                short4v pf = pack4(e[t2][0] * linv, e[t2][1] * linv,
                                   e[t2][2] * linv, e[t2][3] * linv);
                short4v alo = *(const short4v*)&aT[c * 64 + t2 * 16 + u * 4];
                short4v ahi = *(const short4v*)&aT[(c + 16) * 64 + t2 * 16 + u * 4];
                qlo = __builtin_amdgcn_mfma_f32_16x16x16bf16_1k(alo, pf, qlo, 0, 0, 0);
                qhi = __builtin_amdgcn_mfma_f32_16x16x16bf16_1k(ahi, pf, qhi, 0, 0, 0);
            }
            u16* dst = &qcb[(bh2 * NN + n0 + r0 + c) * HD];
            *(short4v*)&dst[u * 4]      = pack4(qlo[0] * QSC, qlo[1] * QSC, qlo[2] * QSC, qlo[3] * QSC);
            *(short4v*)&dst[16 + u * 4] = pack4(qhi[0] * QSC, qhi[1] * QSC, qhi[2] * QSC, qhi[3] * QSC);
        }
    }
}

// ---------------------------------------------------------------------------
// stage 2 flash: LDS double-buffer via global_load_lds. Wave = 32 q-rows,
// tile = 128 keys. O partials stored NORMALIZED bf16 (+ l per split).
// grid (25, NHD*NSPLIT, NB) x 256.
__global__ __launch_bounds__(256, 3) void k_flash4(const u16* __restrict__ qc,
                                                   const u16* __restrict__ kb,
                                                   const u16* __restrict__ vt,
                                                   u16* __restrict__ opb,
                                                   float* __restrict__ lp) {
    __shared__ __align__(16) u16 Ks[2][4096];
    __shared__ __align__(16) u16 Vs[2][4096];
    int b = blockIdx.z;
    int h = blockIdx.y & 3;
    int s = blockIdx.y >> 2;
    int w = threadIdx.x >> 6, lane = threadIdx.x & 63;
    int c = lane & 15, u = lane >> 4;
    int qa = blockIdx.x * 128 + w * 32;
    int qbr = qa + 16;
    if (qa  > NN - 16) qa  = NN - 16;
    if (qbr > NN - 16) qbr = NN - 16;
    size_t bh = (size_t)b * NHD + h;
    const u16* kg = kb + bh * (size_t)NKP * HD;
    const u16* vg = vt + bh * (size_t)NTILE * 4096;
    short8 qfA = *(const short8*)(qc + (bh * NN + qa  + c) * HD + u * 8);
    short8 qfB = *(const short8*)(qc + (bh * NN + qbr + c) * HD + u * 8);
    const f32x4 z = {0.f, 0.f, 0.f, 0.f};
    f32x4 oA0 = z, oA1 = z, oB0 = z, oB1 = z;
    float lA = 0.f, lB = 0.f;
    int t0 = (s * NTILE) / NSPLIT, t1 = ((s + 1) * NTILE) / NSPLIT;
    stage8k(kg + (size_t)t0 * 4096, &Ks[0][0], w, lane);
    stage8k(vg + (size_t)t0 * 4096, &Vs[0][0], w, lane);
#pragma unroll 1
    for (int t = t0; t < t1; ++t) {
        int buf = (t - t0) & 1;
        __syncthreads();
        if (t + 1 < t1) {
            stage8k(kg + (size_t)(t + 1) * 4096, &Ks[buf ^ 1][0], w, lane);
            stage8k(vg + (size_t)(t + 1) * 4096, &Vs[buf ^ 1][0], w, lane);
        }
        const u16* kp = &Ks[buf][0];
        const u16* vp = &Vs[buf][0];
        int kk = t * 128;
        bool tail = (kk + 128 > NN);
#pragma unroll
        for (int sub = 0; sub < 8; ++sub) {
            short8 kf = *(const short8*)(kp + sub * 512 + c * 32 + u * 8);
            f32x4 sA = __builtin_amdgcn_mfma_f32_16x16x32_bf16(kf, qfA, z, 0, 0, 0);
            f32x4 sB = __builtin_amdgcn_mfma_f32_16x16x32_bf16(kf, qfB, z, 0, 0, 0);
            float eA[4], eB[4];
#pragma unroll
            for (int r = 0; r < 4; ++r) {
                eA[r] = __builtin_amdgcn_exp2f(sA[r]);
                eB[r] = __builtin_amdgcn_exp2f(sB[r]);
            }
            if (tail) {
#pragma unroll
                for (int r = 0; r < 4; ++r)
                    if (kk + sub * 16 + u * 4 + r >= NN) { eA[r] = 0.f; eB[r] = 0.f; }
            }
            lA += (eA[0] + eA[1]) + (eA[2] + eA[3]);
            lB += (eB[0] + eB[1]) + (eB[2] + eB[3]);
            short4v pA = pack4(eA[0], eA[1], eA[2], eA[3]);
            short4v pB = pack4(eB[0], eB[1], eB[2], eB[3]);
            short4v va = *(const short4v*)(vp + sub * 512 + u * 128 + c * 4);
            short4v vb = *(const short4v*)(vp + sub * 512 + u * 128 + (c + 16) * 4);
            oA0 = __builtin_amdgcn_mfma_f32_16x16x16bf16_1k(va, pA, oA0, 0, 0, 0);
            oA1 = __builtin_amdgcn_mfma_f32_16x16x16bf16_1k(vb, pA, oA1, 0, 0, 0);
            oB0 = __builtin_amdgcn_mfma_f32_16x16x16bf16_1k(va, pB, oB0, 0, 0, 0);
            oB1 = __builtin_amdgcn_mfma_f32_16x16x16bf16_1k(vb, pB, oB1, 0, 0, 0);
        }
    }
    lA += __shfl_xor(lA, 16); lA += __shfl_xor(lA, 32);
    lB += __shfl_xor(lB, 16); lB += __shfl_xor(lB, 32);
    float iA = 1.f / lA, iB = 1.f / lB;
    u16* oba = opb + (((size_t)(s * NB + b)) * NN + qa + c) * NC + h * HD;
    *(short4v*)&oba[u * 4]      = pack4(oA0[0] * iA, oA0[1] * iA, oA0[2] * iA, oA0[3] * iA);
    *(short4v*)&oba[16 + u * 4] = pack4(oA1[0] * iA, oA1[1] * iA, oA1[2] * iA, oA1[3] * iA);
    u16* obb = opb + (((size_t)(s * NB + b)) * NN + qbr + c) * NC + h * HD;
    *(short4v*)&obb[u * 4]      = pack4(oB0[0] * iB, oB0[1] * iB, oB0[2] * iB, oB0[3] * iB);
    *(short4v*)&obb[16 + u * 4] = pack4(oB1[0] * iB, oB1[1] * iB, oB1[2] * iB, oB1[3] * iB);
    if (u == 0) {
        lp[(((size_t)(s * NB + b)) * NHD + h) * NN + qa  + c] = lA;
        lp[(((size_t)(s * NB + b)) * NHD + h) * NN + qbr + c] = lB;
    }
}

// ---------------------------------------------------------------------------
// proj + LN via MFMA. Block = 16 rows: weighted-combine NSPLIT normalized
// bf16 partials (weights l_s) -> bf16 A in LDS -> MFMA vs wpb -> per-row LN
// -> vectorized NCHW store. grid 392 x 256.
__global__ __launch_bounds__(256, 4) void k_proj2(const u16* __restrict__ opb,
                                                  const float* __restrict__ lp,
                                                  const u16* __restrict__ wpb,
                                                  const float* __restrict__ bgb,
                                                  void* __restrict__ out,
                                                  const int* __restrict__ flag) {
    __shared__ u16 Af[16 * 136];
    __shared__ float red1[4][16], red2[4][16];
    int bx = blockIdx.x;
    int b = bx >= 196;
    int n0 = (bx - b * 196) * 16;
    int t = threadIdx.x;
    {   // combine: thread t -> row t>>4, channels (t&15)*8..+7
        int row = t >> 4, c8 = (t & 15) * 8;
        int n = n0 + row;
        int hh = c8 >> 5;
        float num[8] = {};
        float den = 0.f;
#pragma unroll
        for (int s = 0; s < NSPLIT; ++s) {
            float ls = lp[(((size_t)(s * NB + b)) * NHD + hh) * NN + n];
            short8 o8 = *(const short8*)&opb[(((size_t)(s * NB + b)) * NN + n) * NC + c8];
            den += ls;
#pragma unroll
            for (int i = 0; i < 8; ++i) num[i] += ls * b2f((u16)o8[i]);
        }
        float inv = 1.f / den;
        u16* dst = &Af[row * 136 + c8];
#pragma unroll
        for (int i = 0; i < 8; i += 2) {
            __hip_bfloat162 p = __float22bfloat162_rn(
                make_float2(num[i] * inv, num[i + 1] * inv));
            *(uint32_t*)&dst[i] = *(uint32_t*)&p;
        }
    }
    __syncthreads();
    int w = t >> 6, lane = t & 63, c = lane & 15, u = lane >> 4;
    int oA = w * 32 + c, oB = w * 32 + 16 + c;
    const f32x4 z = {0.f, 0.f, 0.f, 0.f};
    f32x4 cA = z, cB = z;
#pragma unroll
    for (int kf = 0; kf < 4; ++kf) {
        short8 a  = *(const short8*)&Af[c * 136 + kf * 32 + u * 8];
        short8 bA = *(const short8*)&wpb[(size_t)oA * 128 + kf * 32 + u * 8];
        short8 bB = *(const short8*)&wpb[(size_t)oB * 128 + kf * 32 + u * 8];
        cA = __builtin_amdgcn_mfma_f32_16x16x32_bf16(a, bA, cA, 0, 0, 0);
        cB = __builtin_amdgcn_mfma_f32_16x16x32_bf16(a, bB, cB, 0, 0, 0);
    }
    float bpA = bgb[oA], bpB = bgb[oB];
    float s1[4], s2[4];
#pragma unroll
    for (int r = 0; r < 4; ++r) {
        cA[r] += bpA; cB[r] += bpB;
        s1[r] = cA[r] + cB[r];
        s2[r] = cA[r] * cA[r] + cB[r] * cB[r];
    }
#pragma unroll
    for (int off = 1; off < 16; off <<= 1)
#pragma unroll
        for (int r = 0; r < 4; ++r) {
            s1[r] += __shfl_xor(s1[r], off);
            s2[r] += __shfl_xor(s2[r], off);
        }
    if (c == 0)
#pragma unroll
        for (int r = 0; r < 4; ++r) {
            red1[w][u * 4 + r] = s1[r];
            red2[w][u * 4 + r] = s2[r];
        }
    __syncthreads();
    float gA = bgb[128 + oA], beA = bgb[256 + oA];
    float gB = bgb[128 + oB], beB = bgb[256 + oB];
    float outA[4], outB[4];
#pragma unroll
    for (int r = 0; r < 4; ++r) {
        int row = u * 4 + r;
        float S1 = (red1[0][row] + red1[1][row]) + (red1[2][row] + red1[3][row]);
        float S2 = (red2[0][row] + red2[1][row]) + (red2[2][row] + red2[3][row]);
        float mu = S1 * (1.f / NC);
        float ex = S2 * (1.f / NC);
        float rstd = rsqrtf(ex - mu * mu + 1e-5f);
        outA[r] = (cA[r] - mu) * rstd * gA + beA;
        outB[r] = (cB[r] - mu) * rstd * gB + beB;
    }
    int n = n0 + u * 4;   // 4 consecutive rows per lane
    if (*flag) {
        __hip_bfloat16* ob = (__hip_bfloat16*)out;
        ushort4 sA = make_ushort4(bfb(outA[0]), bfb(outA[1]), bfb(outA[2]), bfb(outA[3]));
        ushort4 sB = make_ushort4(bfb(outB[0]), bfb(outB[1]), bfb(outB[2]), bfb(outB[3]));
        *(ushort4*)&ob[((size_t)(b * NC + oA)) * NN + n] = sA;
        *(ushort4*)&ob[((size_t)(b * NC + oB)) * NN + n] = sB;
    } else {
        float* ob = (float*)out;
        *(float4*)&ob[((size_t)(b * NC + oA)) * NN + n] = make_float4(outA[0], outA[1], outA[2], outA[3]);
        *(float4*)&ob[((size_t)(b * NC + oB)) * NN + n] = make_float4(outB[0], outB[1], outB[2], outB[3]);
    }
}

// ---------------------------------------------------------------------------
extern "C" void kernel_launch(void* const* d_in, const int* in_sizes, int n_in,
                              void* d_out, int out_size, void* d_ws, size_t ws_size,
                              hipStream_t stream) {
    const void* x_raw  = d_in[0];
    const void* wq_raw = d_in[1];
    const void* wp_raw = d_in[2];
    const void* bp_raw = d_in[3];
    const void* lg_raw = d_in[4];
    const void* lb_raw = d_in[5];

    float* ws   = (float*)d_ws;
    int*   flag = (int*)d_ws;
    float* bgb  = ws + 16;                              // 512
    float* lp   = bgb + 512;                            // 4*2*4*3136
    u16*   opb  = (u16*)(lp + (size_t)NSPLIT * NB * NHD * NN);  // 4*2*3136*128
    u16*   xT   = opb + (size_t)NSPLIT * NB * NN * NC;
    u16*   wbf  = xT + (size_t)NB * NN * NC;            // 49152
    u16*   wpb  = wbf + 3 * NC * NC;                    // 16384
    u16*   kbf  = wpb + NC * NC;                        // padded keys
    u16*   vtb  = kbf + (size_t)NB * NHD * NKP * HD;    // fragmented tiles
    u16*   qcb  = vtb + (size_t)NB * NHD * NTILE * 4096;
    u16*   agb  = qcb + (size_t)NB * NHD * NN * HD;     // 16384
    u16*   agT  = agb + NB * NHD * 64 * 32;             // 16384
    // total ~13.5 MB

    k_prep<<<729, 256, 0, stream>>>(x_raw, wq_raw, wp_raw, bp_raw, lg_raw, lb_raw,
                                    xT, wbf, wpb, bgb, agb, agT, flag);
    k_qkv_s1<<<dim3(NN / 64, 6, NB), 256, 0, stream>>>(xT, wbf, agb, agT,
                                                       kbf, vtb, qcb);
    k_flash4<<<dim3(25, NHD * NSPLIT, NB), 256, 0, stream>>>(qcb, kbf, vtb, opb, lp);
    k_proj2<<<392, 256, 0, stream>>>(opb, lp, wpb, bgb, d_out, flag);
}

// Round 8
// 115.493 us; speedup vs baseline: 1.9063x; 1.0327x over previous
//
#include <hip/hip_runtime.h>
#include <hip/hip_bf16.h>
#include <stdint.h>

typedef unsigned short u16;
typedef __attribute__((ext_vector_type(8))) short short8;   // 8 bf16 (4 VGPRs)
typedef __attribute__((ext_vector_type(4))) short short4v;  // 4 bf16 (2 VGPRs)
typedef __attribute__((ext_vector_type(4))) float f32x4;    // MFMA C/D

#define NB 2
#define NC 128
#define NHD 4      // heads
#define HD 32      // head dim
#define NN 3136    // H*W
#define NA 49      // agent tokens
#define NSPLIT 4   // flash K-split
#define NKP 3200   // padded key count (25 tiles of 128)
#define NTILE 25
#define SCALE 0.17677669529663687f  // 1/sqrt(32)
#define LOG2E 1.4426950408889634f
#define QSC (SCALE * LOG2E)

__device__ inline u16 bfb(float f) {
    __hip_bfloat16 h = __float2bfloat16(f);
    return *(u16*)&h;
}
__device__ inline float b2f(u16 w) {
    return __uint_as_float(((uint32_t)w) << 16);
}
__device__ inline short4v pack4(float a, float b, float c, float d) {
    union { short4v s; __hip_bfloat162 h[2]; } u;
    u.h[0] = __float22bfloat162_rn(make_float2(a, b));
    u.h[1] = __float22bfloat162_rn(make_float2(c, d));
    return u.s;
}
__device__ inline float ldf(const void* p, size_t i, int f) {
    return f ? b2f(((const u16*)p)[i]) : ((const float*)p)[i];
}
// async global->LDS, 16B per lane; lds dest = uniform base + lane*16
__device__ inline void gld16(const u16* g, u16* l) {
    __builtin_amdgcn_global_load_lds(
        (__attribute__((address_space(1))) void*)(g),
        (__attribute__((address_space(3))) void*)(l), 16, 0, 0);
}
__device__ inline void stage8k(const u16* g, u16* lds, int w, int lane) {
    gld16(g + (size_t)(w * 64 + lane) * 8,       lds + (size_t)w * 512);
    gld16(g + (size_t)(256 + w * 64 + lane) * 8, lds + 2048 + (size_t)w * 512);
}
// per-block dtype detect (deterministic; all 256 threads participate)
__device__ inline int detect_local(const u16* raw, int t) {
    __shared__ int cnt;
    if (t == 0) cnt = 0;
    __syncthreads();
    float a = fabsf(b2f(raw[t * 97]));
    if (a >= 1e-4f && a <= 100.0f) atomicAdd(&cnt, 1);
    __syncthreads();
    return cnt >= 230;
}

// ---------------------------------------------------------------------------
// fused prep:
// [0,392)   x -> xTs bf16, GRANULE-TRANSPOSED per 64-row tile:
//           elem (b, tile T, ktu=c>>3, n_loc, c&7) at
//           ((b*49+T)*16 + ktu)*512 + n_loc*8 + (c&7)
// [392,584) wqkv -> wbf bf16 [o][c] (natural)
// [584,648) wproj -> wps bf16 granule-transposed: ((otile*16+ktu)*16+oloc)*8+wi
// [648,650) biases -> bgb (+flag)
// [650,729) agent 8x8 pool from RAW x -> agb/agT
__global__ __launch_bounds__(256) void k_prep(const void* __restrict__ xr,
                                              const void* __restrict__ wq,
                                              const void* __restrict__ wp,
                                              const void* __restrict__ bp,
                                              const void* __restrict__ g,
                                              const void* __restrict__ bb,
                                              u16* __restrict__ xTs,
                                              u16* __restrict__ wbf,
                                              u16* __restrict__ wps,
                                              float* __restrict__ bgb,
                                              u16* __restrict__ agb,
                                              u16* __restrict__ agT,
                                              int* __restrict__ flagOut) {
    __shared__ u16 tile[128][18];
    int bx = blockIdx.x, t = threadIdx.x;
    int f = detect_local((const u16*)xr, t);
    if (bx < 392) {
        int b = bx / 196;
        int n0 = (bx % 196) * 16;
        int T = n0 >> 6, nbase = n0 & 63;
        int c = t >> 1, nh = (t & 1) * 8;
        size_t src = ((size_t)(b * 128 + c)) * NN + n0 + nh;
#pragma unroll
        for (int i = 0; i < 8; ++i) tile[c][nh + i] = bfb(ldf(xr, src + i, f));
        __syncthreads();
        int n = t >> 4, ktu = t & 15;
        int c0 = ktu * 8;
        short8 o;
#pragma unroll
        for (int i = 0; i < 8; ++i) o[i] = (short)tile[c0 + i][n];
        *(short8*)&xTs[(((size_t)b * 49 + T) * 16 + ktu) * 512 + (nbase + n) * 8] = o;
    } else if (bx < 584) {
        int i = (bx - 392) * 256 + t;
        wbf[i] = bfb(ldf(wq, i, f));
    } else if (bx < 648) {
        int i = (bx - 584) * 256 + t;
        int o = i >> 7, c = i & 127;
        int otile = o >> 4, oloc = o & 15, ktu = c >> 3, wi = c & 7;
        wps[((otile * 16 + ktu) * 16 + oloc) * 8 + wi] = bfb(ldf(wp, i, f));
    } else if (bx < 650) {
        int i = (bx - 648) * 256 + t;
        if (i < 128)      bgb[i] = ldf(bp, i, f);
        else if (i < 256) bgb[i] = ldf(g, i - 128, f);
        else if (i < 384) bgb[i] = ldf(bb, i - 256, f);
        if (bx == 648 && t == 0) *flagOut = f;
    } else {
        int idx = (bx - 650) * 256 + t;
        const int NPOOL = NB * NC * NA;   // 12544
        if (idx < NPOOL) {
            int b = idx / (NC * NA);
            int r = idx % (NC * NA);
            int c = r / NA;
            int a = r % NA;
            int ai = a / 7, aj = a % 7;
            size_t base = ((size_t)(b * NC + c)) * NN + ai * 8 * 56 + aj * 8;
            float s = 0.f;
            if (f) {
                const u16* xp = (const u16*)xr + base;
#pragma unroll
                for (int uu = 0; uu < 8; ++uu) {
                    ushort4 a0 = *(const ushort4*)&xp[uu * 56];
                    ushort4 a1 = *(const ushort4*)&xp[uu * 56 + 4];
                    s += b2f(a0.x) + b2f(a0.y) + b2f(a0.z) + b2f(a0.w)
                       + b2f(a1.x) + b2f(a1.y) + b2f(a1.z) + b2f(a1.w);
                }
            } else {
                const float* xp = (const float*)xr + base;
#pragma unroll
                for (int uu = 0; uu < 8; ++uu) {
                    float4 v0 = *(const float4*)&xp[uu * 56];
                    float4 v1 = *(const float4*)&xp[uu * 56 + 4];
                    s += v0.x + v0.y + v0.z + v0.w + v1.x + v1.y + v1.z + v1.w;
                }
            }
            int h = c >> 5, d = c & 31;
            int bh = b * NHD + h;
            u16 val = bfb(s * (1.f / 64.f));
            agb[bh * 2048 + a * 32 + d] = val;
            agT[bh * 2048 + d * 64 + a] = val;
        } else {
            int j = idx - NPOOL;
            if (j < 3840) {
                int bh = j / 480, rem = j % 480;
                int a = 49 + rem / 32, d = rem % 32;
                agb[bh * 2048 + a * 32 + d] = 0;
            } else if (j < 7680) {
                j -= 3840;
                int bh = j / 480, rem = j % 480;
                int a = 49 + rem / 32, d = rem % 32;
                agT[bh * 2048 + d * 64 + a] = 0;
            }
        }
    }
}

// ---------------------------------------------------------------------------
// QKV + fused stage-1. grid (49, 6, NB) x 256.
// B-tile (64n x 128c) staged ONCE per block via global_load_lds from the
// granule-transposed xTs -> conflict-free ds_read_b128 frags shared by all
// 4 waves. y<2: q -> LDS, then stage1 -> qcb. y2-3: k in FRAGMENTED granule
// layout [bh][tile][sub][dgran][key][8] (so flash K-reads are conflict-free).
// y4-5: v pre-fragmented (as before).
__global__ __launch_bounds__(256, 4) void k_qkv_s1(const u16* __restrict__ xTs,
                                                   const u16* __restrict__ wbf,
                                                   const u16* __restrict__ agb,
                                                   const u16* __restrict__ agT,
                                                   u16* __restrict__ kbf,
                                                   u16* __restrict__ vtb,
                                                   u16* __restrict__ qcb) {
    __shared__ __align__(16) u16 xs[8192];          // 16 KB staged B-tile
    __shared__ u16 qtile[2 * 64 * 40];              // [head][row][32 d]
    int b = blockIdx.z;
    int n0 = blockIdx.x * 64;
    int w = threadIdx.x >> 6, lane = threadIdx.x & 63;
    int c = lane & 15, u = lane >> 4;
    int t = threadIdx.x;
    // stage the 64-row B-tile (contiguous 16 KB in xTs)
    const u16* xtile = xTs + (((size_t)b * 49 + (n0 >> 6)) * 16) * 512;
#pragma unroll
    for (int i = 0; i < 4; ++i)
        gld16(xtile + (size_t)(i * 256 + t) * 8, xs + (size_t)(i * 256 + t) * 8);
    int o0 = blockIdx.y * 64 + w * 16;
    const f32x4 z = {0.f, 0.f, 0.f, 0.f};
    short8 af0 = *(const short8*)&wbf[(o0 + c) * 128 +  0 + u * 8];
    short8 af1 = *(const short8*)&wbf[(o0 + c) * 128 + 32 + u * 8];
    short8 af2 = *(const short8*)&wbf[(o0 + c) * 128 + 64 + u * 8];
    short8 af3 = *(const short8*)&wbf[(o0 + c) * 128 + 96 + u * 8];
    int tq = o0 >> 7, h = (o0 >> 5) & 3, d0 = (o0 & 31) + u * 4;
    size_t bh = (size_t)b * NHD + h;
    __syncthreads();   // drains staging (vmcnt(0) before barrier)
#pragma unroll
    for (int nt = 0; nt < 4; ++nt) {
        int n = n0 + nt * 16 + c;
        f32x4 acc = z;
        acc = __builtin_amdgcn_mfma_f32_16x16x32_bf16(af0,
            *(const short8*)&xs[((0 * 4 + u) * 64 + nt * 16 + c) * 8], acc, 0, 0, 0);
        acc = __builtin_amdgcn_mfma_f32_16x16x32_bf16(af1,
            *(const short8*)&xs[((1 * 4 + u) * 64 + nt * 16 + c) * 8], acc, 0, 0, 0);
        acc = __builtin_amdgcn_mfma_f32_16x16x32_bf16(af2,
            *(const short8*)&xs[((2 * 4 + u) * 64 + nt * 16 + c) * 8], acc, 0, 0, 0);
        acc = __builtin_amdgcn_mfma_f32_16x16x32_bf16(af3,
            *(const short8*)&xs[((3 * 4 + u) * 64 + nt * 16 + c) * 8], acc, 0, 0, 0);
        if (tq == 0) {
            int hl = (o0 >> 5) & 1;
            *(short4v*)&qtile[(hl * 64 + nt * 16 + c) * 40 + d0] =
                pack4(acc[0] * QSC, acc[1] * QSC, acc[2] * QSC, acc[3] * QSC);
        } else if (tq == 1) {
            int tile = n >> 7, sub = (n >> 4) & 7, key = n & 15;
            int dg = d0 >> 3, wi = d0 & 7;
            size_t kb0 = (((size_t)bh * NTILE + tile) * 8 + sub) * 4 + dg;
            *(short4v*)&kbf[kb0 * 128 + key * 8 + wi] =
                pack4(acc[0], acc[1], acc[2], acc[3]);
        } else {
            int tile = n >> 7, kt2 = n & 127;
            int sub = kt2 >> 4, uu = (kt2 >> 2) & 3, jj = n & 3;
            size_t vb0 = ((size_t)bh * NTILE + tile) * 4096 + sub * 512 + uu * 128 + jj;
#pragma unroll
            for (int r = 0; r < 4; ++r)
                vtb[vb0 + (d0 + r) * 4] = bfb(acc[r]);
        }
    }
    if (blockIdx.y < 2) {
        __syncthreads();
        // stage1: 8 tiles (2 heads x 4 row-groups); wave w takes tiles w, w+4
#pragma unroll
        for (int tt = w; tt < 8; tt += 4) {
            int hl2 = tt >> 2, r0 = (tt & 3) * 16;
            int hg = blockIdx.y * 2 + hl2;
            size_t bh2 = (size_t)b * NHD + hg;
            const u16* aB = agb + bh2 * 2048;
            const u16* aT = agT + bh2 * 2048;
            short8 qf = *(const short8*)&qtile[(hl2 * 64 + r0 + c) * 40 + u * 8];
            f32x4 st[4];
#pragma unroll
            for (int t2 = 0; t2 < 4; ++t2) {
                short8 afr = *(const short8*)&aB[(t2 * 16 + c) * 32 + u * 8];
                st[t2] = __builtin_amdgcn_mfma_f32_16x16x32_bf16(afr, qf, z, 0, 0, 0);
            }
            float e[4][4];
            float lsum = 0.f;
#pragma unroll
            for (int t2 = 0; t2 < 4; ++t2)
#pragma unroll
                for (int r = 0; r < 4; ++r) {
                    float v = __builtin_amdgcn_exp2f(st[t2][r]);
                    if (t2 == 3 && !(u == 0 && r == 0)) v = 0.f;   // agents >= 49
                    e[t2][r] = v;
                    lsum += v;
                }
            lsum += __shfl_xor(lsum, 16);
            lsum += __shfl_xor(lsum, 32);
            float linv = 1.f / lsum;
            f32x4 qlo = z, qhi = z;
#pragma unroll
            for (int t2 = 0; t2 < 4; ++t2) {
                short4v pf = pack4(e[t2][0] * linv, e[t2][1] * linv,
                                   e[t2][2] * linv, e[t2][3] * linv);
                short4v alo = *(const short4v*)&aT[c * 64 + t2 * 16 + u * 4];
                short4v ahi = *(const short4v*)&aT[(c + 16) * 64 + t2 * 16 + u * 4];
                qlo = __builtin_amdgcn_mfma_f32_16x16x16bf16_1k(alo, pf, qlo, 0, 0, 0);
                qhi = __builtin_amdgcn_mfma_f32_16x16x16bf16_1k(ahi, pf, qhi, 0, 0, 0);
            }
            u16* dst = &qcb[(bh2 * NN + n0 + r0 + c) * HD];
            *(short4v*)&dst[u * 4]      = pack4(qlo[0] * QSC, qlo[1] * QSC, qlo[2] * QSC, qlo[3] * QSC);
            *(short4v*)&dst[16 + u * 4] = pack4(qhi[0] * QSC, qhi[1] * QSC, qhi[2] * QSC, qhi[3] * QSC);
        }
    }
}

// ---------------------------------------------------------------------------
// stage 2 flash: LDS double-buffer via global_load_lds. K now granule-
// fragmented -> S-frag ds_read_b128 conflict-free (lane stride 4 dwords).
// grid (25, NHD*NSPLIT, NB) x 256.
__global__ __launch_bounds__(256, 3) void k_flash4(const u16* __restrict__ qc,
                                                   const u16* __restrict__ kb,
                                                   const u16* __restrict__ vt,
                                                   u16* __restrict__ opb,
                                                   float* __restrict__ lp) {
    __shared__ __align__(16) u16 Ks[2][4096];
    __shared__ __align__(16) u16 Vs[2][4096];
    int b = blockIdx.z;
    int h = blockIdx.y & 3;
    int s = blockIdx.y >> 2;
    int w = threadIdx.x >> 6, lane = threadIdx.x & 63;
    int c = lane & 15, u = lane >> 4;
    int qa = blockIdx.x * 128 + w * 32;
    int qbr = qa + 16;
    if (qa  > NN - 16) qa  = NN - 16;
    if (qbr > NN - 16) qbr = NN - 16;
    size_t bh = (size_t)b * NHD + h;
    const u16* kg = kb + bh * (size_t)NTILE * 4096;
    const u16* vg = vt + bh * (size_t)NTILE * 4096;
    short8 qfA = *(const short8*)(qc + (bh * NN + qa  + c) * HD + u * 8);
    short8 qfB = *(const short8*)(qc + (bh * NN + qbr + c) * HD + u * 8);
    const f32x4 z = {0.f, 0.f, 0.f, 0.f};
    f32x4 oA0 = z, oA1 = z, oB0 = z, oB1 = z;
    float lA = 0.f, lB = 0.f;
    int t0 = (s * NTILE) / NSPLIT, t1 = ((s + 1) * NTILE) / NSPLIT;
    stage8k(kg + (size_t)t0 * 4096, &Ks[0][0], w, lane);
    stage8k(vg + (size_t)t0 * 4096, &Vs[0][0], w, lane);
#pragma unroll 1
    for (int t = t0; t < t1; ++t) {
        int buf = (t - t0) & 1;
        __syncthreads();
        if (t + 1 < t1) {
            stage8k(kg + (size_t)(t + 1) * 4096, &Ks[buf ^ 1][0], w, lane);
            stage8k(vg + (size_t)(t + 1) * 4096, &Vs[buf ^ 1][0], w, lane);
        }
        const u16* kp = &Ks[buf][0];
        const u16* vp = &Vs[buf][0];
        int kk = t * 128;
        bool tail = (kk + 128 > NN);
#pragma unroll
        for (int sub = 0; sub < 8; ++sub) {
            // K granule layout: [sub][dgran=u][key][8] -> lane stride 4 dwords
            short8 kf = *(const short8*)(kp + ((sub * 4 + u) * 16 + c) * 8);
            f32x4 sA = __builtin_amdgcn_mfma_f32_16x16x32_bf16(kf, qfA, z, 0, 0, 0);
            f32x4 sB = __builtin_amdgcn_mfma_f32_16x16x32_bf16(kf, qfB, z, 0, 0, 0);
            float eA[4], eB[4];
#pragma unroll
            for (int r = 0; r < 4; ++r) {
                eA[r] = __builtin_amdgcn_exp2f(sA[r]);
                eB[r] = __builtin_amdgcn_exp2f(sB[r]);
            }
            if (tail) {
#pragma unroll
                for (int r = 0; r < 4; ++r)
                    if (kk + sub * 16 + u * 4 + r >= NN) { eA[r] = 0.f; eB[r] = 0.f; }
            }
            lA += (eA[0] + eA[1]) + (eA[2] + eA[3]);
            lB += (eB[0] + eB[1]) + (eB[2] + eB[3]);
            short4v pA = pack4(eA[0], eA[1], eA[2], eA[3]);
            short4v pB = pack4(eB[0], eB[1], eB[2], eB[3]);
            short4v va = *(const short4v*)(vp + sub * 512 + u * 128 + c * 4);
            short4v vb = *(const short4v*)(vp + sub * 512 + u * 128 + (c + 16) * 4);
            oA0 = __builtin_amdgcn_mfma_f32_16x16x16bf16_1k(va, pA, oA0, 0, 0, 0);
            oA1 = __builtin_amdgcn_mfma_f32_16x16x16bf16_1k(vb, pA, oA1, 0, 0, 0);
            oB0 = __builtin_amdgcn_mfma_f32_16x16x16bf16_1k(va, pB, oB0, 0, 0, 0);
            oB1 = __builtin_amdgcn_mfma_f32_16x16x16bf16_1k(vb, pB, oB1, 0, 0, 0);
        }
    }
    lA += __shfl_xor(lA, 16); lA += __shfl_xor(lA, 32);
    lB += __shfl_xor(lB, 16); lB += __shfl_xor(lB, 32);
    float iA = 1.f / lA, iB = 1.f / lB;
    u16* oba = opb + (((size_t)(s * NB + b)) * NN + qa + c) * NC + h * HD;
    *(short4v*)&oba[u * 4]      = pack4(oA0[0] * iA, oA0[1] * iA, oA0[2] * iA, oA0[3] * iA);
    *(short4v*)&oba[16 + u * 4] = pack4(oA1[0] * iA, oA1[1] * iA, oA1[2] * iA, oA1[3] * iA);
    u16* obb = opb + (((size_t)(s * NB + b)) * NN + qbr + c) * NC + h * HD;
    *(short4v*)&obb[u * 4]      = pack4(oB0[0] * iB, oB0[1] * iB, oB0[2] * iB, oB0[3] * iB);
    *(short4v*)&obb[16 + u * 4] = pack4(oB1[0] * iB, oB1[1] * iB, oB1[2] * iB, oB1[3] * iB);
    if (u == 0) {
        lp[(((size_t)(s * NB + b)) * NHD + h) * NN + qa  + c] = lA;
        lp[(((size_t)(s * NB + b)) * NHD + h) * NN + qbr + c] = lB;
    }
}

// ---------------------------------------------------------------------------
// proj + LN via MFMA. Weight tile (32 KB, granule-transposed wps) staged once
// per block via global_load_lds -> conflict-free ds frags shared by 4 waves.
// grid 392 x 256.
__global__ __launch_bounds__(256, 4) void k_proj2(const u16* __restrict__ opb,
                                                  const float* __restrict__ lp,
                                                  const u16* __restrict__ wps,
                                                  const float* __restrict__ bgb,
                                                  void* __restrict__ out,
                                                  const int* __restrict__ flag) {
    __shared__ __align__(16) u16 wl[16384];   // 32 KB staged weights
    __shared__ u16 Af[16 * 136];
    __shared__ float red1[4][16], red2[4][16];
    int bx = blockIdx.x;
    int b = bx >= 196;
    int n0 = (bx - b * 196) * 16;
    int t = threadIdx.x;
#pragma unroll
    for (int i = 0; i < 8; ++i)
        gld16(wps + (size_t)(i * 256 + t) * 8, wl + (size_t)(i * 256 + t) * 8);
    {   // combine: thread t -> row t>>4, channels (t&15)*8..+7
        int row = t >> 4, c8 = (t & 15) * 8;
        int n = n0 + row;
        int hh = c8 >> 5;
        float num[8] = {};
        float den = 0.f;
#pragma unroll
        for (int s = 0; s < NSPLIT; ++s) {
            float ls = lp[(((size_t)(s * NB + b)) * NHD + hh) * NN + n];
            short8 o8 = *(const short8*)&opb[(((size_t)(s * NB + b)) * NN + n) * NC + c8];
            den += ls;
#pragma unroll
            for (int i = 0; i < 8; ++i) num[i] += ls * b2f((u16)o8[i]);
        }
        float inv = 1.f / den;
        u16* dst = &Af[row * 136 + c8];
#pragma unroll
        for (int i = 0; i < 8; i += 2) {
            __hip_bfloat162 p = __float22bfloat162_rn(
                make_float2(num[i] * inv, num[i + 1] * inv));
            *(uint32_t*)&dst[i] = *(uint32_t*)&p;
        }
    }
    __syncthreads();   // drains weight staging + Af writes
    int w = t >> 6, lane = t & 63, c = lane & 15, u = lane >> 4;
    int oA = w * 32 + c, oB = w * 32 + 16 + c;
    const f32x4 z = {0.f, 0.f, 0.f, 0.f};
    f32x4 cA = z, cB = z;
#pragma unroll
    for (int kf = 0; kf < 4; ++kf) {
        short8 a  = *(const short8*)&Af[c * 136 + kf * 32 + u * 8];
        short8 bA = *(const short8*)&wl[(((2 * w) * 16 + kf * 4 + u) * 16 + c) * 8];
        short8 bB = *(const short8*)&wl[(((2 * w + 1) * 16 + kf * 4 + u) * 16 + c) * 8];
        cA = __builtin_amdgcn_mfma_f32_16x16x32_bf16(a, bA, cA, 0, 0, 0);
        cB = __builtin_amdgcn_mfma_f32_16x16x32_bf16(a, bB, cB, 0, 0, 0);
    }
    float bpA = bgb[oA], bpB = bgb[oB];
    float s1[4], s2[4];
#pragma unroll
    for (int r = 0; r < 4; ++r) {
        cA[r] += bpA; cB[r] += bpB;
        s1[r] = cA[r] + cB[r];
        s2[r] = cA[r] * cA[r] + cB[r] * cB[r];
    }
#pragma unroll
    for (int off = 1; off < 16; off <<= 1)
#pragma unroll
        for (int r = 0; r < 4; ++r) {
            s1[r] += __shfl_xor(s1[r], off);
            s2[r] += __shfl_xor(s2[r], off);
        }
    if (c == 0)
#pragma unroll
        for (int r = 0; r < 4; ++r) {
            red1[w][u * 4 + r] = s1[r];
            red2[w][u * 4 + r] = s2[r];
        }
    __syncthreads();
    float gA = bgb[128 + oA], beA = bgb[256 + oA];
    float gB = bgb[128 + oB], beB = bgb[256 + oB];
    float outA[4], outB[4];
#pragma unroll
    for (int r = 0; r < 4; ++r) {
        int row = u * 4 + r;
        float S1 = (red1[0][row] + red1[1][row]) + (red1[2][row] + red1[3][row]);
        float S2 = (red2[0][row] + red2[1][row]) + (red2[2][row] + red2[3][row]);
        float mu = S1 * (1.f / NC);
        float ex = S2 * (1.f / NC);
        float rstd = rsqrtf(ex - mu * mu + 1e-5f);
        outA[r] = (cA[r] - mu) * rstd * gA + beA;
        outB[r] = (cB[r] - mu) * rstd * gB + beB;
    }
    int n = n0 + u * 4;   // 4 consecutive rows per lane
    if (*flag) {
        __hip_bfloat16* ob = (__hip_bfloat16*)out;
        ushort4 sA = make_ushort4(bfb(outA[0]), bfb(outA[1]), bfb(outA[2]), bfb(outA[3]));
        ushort4 sB = make_ushort4(bfb(outB[0]), bfb(outB[1]), bfb(outB[2]), bfb(outB[3]));
        *(ushort4*)&ob[((size_t)(b * NC + oA)) * NN + n] = sA;
        *(ushort4*)&ob[((size_t)(b * NC + oB)) * NN + n] = sB;
    } else {
        float* ob = (float*)out;
        *(float4*)&ob[((size_t)(b * NC + oA)) * NN + n] = make_float4(outA[0], outA[1], outA[2], outA[3]);
        *(float4*)&ob[((size_t)(b * NC + oB)) * NN + n] = make_float4(outB[0], outB[1], outB[2], outB[3]);
    }
}

// ---------------------------------------------------------------------------
extern "C" void kernel_launch(void* const* d_in, const int* in_sizes, int n_in,
                              void* d_out, int out_size, void* d_ws, size_t ws_size,
                              hipStream_t stream) {
    const void* x_raw  = d_in[0];
    const void* wq_raw = d_in[1];
    const void* wp_raw = d_in[2];
    const void* bp_raw = d_in[3];
    const void* lg_raw = d_in[4];
    const void* lb_raw = d_in[5];

    float* ws   = (float*)d_ws;
    int*   flag = (int*)d_ws;
    float* bgb  = ws + 16;                              // 512
    float* lp   = bgb + 512;                            // 4*2*4*3136
    u16*   opb  = (u16*)(lp + (size_t)NSPLIT * NB * NHD * NN);  // 4*2*3136*128
    u16*   xTs  = opb + (size_t)NSPLIT * NB * NN * NC;  // 802816
    u16*   wbf  = xTs + (size_t)NB * NN * NC;           // 49152
    u16*   wps  = wbf + 3 * NC * NC;                    // 16384
    u16*   kbf  = wps + NC * NC;                        // 25 tiles x 4096 per bh
    u16*   vtb  = kbf + (size_t)NB * NHD * NTILE * 4096;
    u16*   qcb  = vtb + (size_t)NB * NHD * NTILE * 4096;
    u16*   agb  = qcb + (size_t)NB * NHD * NN * HD;     // 16384
    u16*   agT  = agb + NB * NHD * 64 * 32;             // 16384
    // total ~13.5 MB

    k_prep<<<729, 256, 0, stream>>>(x_raw, wq_raw, wp_raw, bp_raw, lg_raw, lb_raw,
                                    xTs, wbf, wps, bgb, agb, agT, flag);
    k_qkv_s1<<<dim3(NN / 64, 6, NB), 256, 0, stream>>>(xTs, wbf, agb, agT,
                                                       kbf, vtb, qcb);
    k_flash4<<<dim3(25, NHD * NSPLIT, NB), 256, 0, stream>>>(qcb, kbf, vtb, opb, lp);
    k_proj2<<<392, 256, 0, stream>>>(opb, lp, wps, bgb, d_out, flag);
}